// Round 6
// baseline (420.544 us; speedup 1.0000x reference)
//
#include <hip/hip_runtime.h>
#include <hip/hip_bf16.h>
#include <hip/hip_fp16.h>
#include <math.h>

// ---------------------------------------------------------------------------
// Diffusion renoise-loop + conditional MLP loss, MI355X (gfx950).
// RNG: threefry_partitionable (bit-exact, absmax 0.0 rounds 1-5).
// Round 6: single mega-kernel for all 8 renoise iterations (1 block = 1 batch,
// survivor-proportional work, zero inter-dispatch overhead) + speculative
// cont + exact repair in k_final; k_loss weights via LDS (s_load round-trips
// were the 69us: VGPR=12 showed full scalarization + lgkmcnt(0) serialization).
#define BS   128
#define NS   1024
#define HID  512
#define CTX  128
#define TT   100
#define ITERS 8

// ---- workspace layout (bytes) ---------------------------------------------
constexpr size_t OFF_SACP  = 0;         // 100 f32
constexpr size_t OFF_S1M   = 512;       // 100 f32
constexpr size_t OFF_KEYS  = 1024;      // 16 u32
constexpr size_t OFF_CNTG  = 1152;      // u32[8][128] -> 5248
constexpr size_t OFF_MASK  = 5248;      // u8[131072] -> 136320
constexpr size_t OFF_BPACK = 262144;    // uint4[128*64*64] = 8 MiB -> 8650752
constexpr size_t OFF_NOISE = 8650752;   // f32[128*1024*3] -> 10223616
constexpr size_t OFF_NOISY = 10223616;  // f32[128*1024*3] -> 11796480
constexpr size_t OFF_BIAS  = 11796480;  // f32[128*512] -> 12058624
constexpr size_t OFF_PA    = 12058624;  // float4[512] -> 12066816
constexpr size_t OFF_PB    = 12066816;  // float4[512] -> 12075008
constexpr size_t OFF_PC    = 12075008;  // f32[512]   -> 12077056
constexpr size_t OFF_PART  = 12077056;  // f32[512]   -> 12079104 (~12.1 MB)

typedef __attribute__((ext_vector_type(8))) _Float16 half8;
typedef __attribute__((ext_vector_type(4))) float f32x4;

// ---- threefry2x32-20 -------------------------------------------------------
__device__ __forceinline__ unsigned rotl32(unsigned x, int r) {
  return (x << r) | (x >> (32 - r));
}
__device__ __forceinline__ void tf2x32(unsigned k0, unsigned k1,
                                       unsigned x0, unsigned x1,
                                       unsigned& o0, unsigned& o1) {
  unsigned k2 = k0 ^ k1 ^ 0x1BD11BDAu;
  x0 += k0; x1 += k1;
#define TF_R4(a,b,c,d) \
  x0 += x1; x1 = rotl32(x1,(a)); x1 ^= x0; \
  x0 += x1; x1 = rotl32(x1,(b)); x1 ^= x0; \
  x0 += x1; x1 = rotl32(x1,(c)); x1 ^= x0; \
  x0 += x1; x1 = rotl32(x1,(d)); x1 ^= x0;
  TF_R4(13,15,26,6)   x0 += k1; x1 += k2 + 1u;
  TF_R4(17,29,16,24)  x0 += k2; x1 += k0 + 2u;
  TF_R4(13,15,26,6)   x0 += k0; x1 += k1 + 3u;
  TF_R4(17,29,16,24)  x0 += k1; x1 += k2 + 4u;
  TF_R4(13,15,26,6)   x0 += k2; x1 += k0 + 5u;
#undef TF_R4
  o0 = x0; o1 = x1;
}

__device__ __forceinline__ float bits_to_u(unsigned bits) {
  float f = __uint_as_float((bits >> 9) | 0x3f800000u) - 1.0f;
  float u = f * 2.0f + (-0.99999994f);
  return fmaxf(-0.99999994f, u);
}

__device__ __forceinline__ float nrm_from_idx(unsigned k0, unsigned k1, unsigned idx) {
  unsigned o0, o1;
  tf2x32(k0, k1, 0u, idx, o0, o1);
  return 1.41421356f * erfinvf(bits_to_u(o0 ^ o1));
}

__device__ __forceinline__ float ftanh(float x) {
  float e = __expf(2.0f * x);
  float r = __builtin_amdgcn_rcpf(e + 1.0f);
  return fmaf(-2.0f, r, 1.0f);
}

// fp16 hi/lo split: x ~= hi + lo with |err| <~ 2^-23 |x|
__device__ __forceinline__ void split16(float x, unsigned short& hi, unsigned short& lo) {
  __half h = __float2half(x);
  float hf = __half2float(h);
  __half l = __float2half(x - hf);
  hi = __half_as_ushort(h);
  lo = __half_as_ushort(l);
}
__device__ __forceinline__ unsigned pack2(unsigned short a, unsigned short b) {
  return (unsigned)a | ((unsigned)b << 16);
}

// ---- kernel 1: tables + iteration keys -------------------------------------
__global__ void k_init(float* __restrict__ sacp, float* __restrict__ s1m,
                       unsigned* __restrict__ keys) {
  __shared__ double omb[TT];
  int t = threadIdx.x;
  if (t < TT) {
    const double PI = 3.14159265358979323846;
    double t0 = (double)t / TT, t1 = (double)(t + 1) / TT;
    double c0 = cos((t0 + 0.008) / 1.008 * PI * 0.5); double ab0 = c0 * c0;
    double c1 = cos((t1 + 0.008) / 1.008 * PI * 0.5); double ab1 = c1 * c1;
    double beta = 1.0 - ab1 / ab0;
    if (beta > 0.999) beta = 0.999;
    omb[t] = 1.0 - beta;
  }
  __syncthreads();
  if (t < TT) {
    double acp = 1.0;
    for (int i = 0; i <= t; ++i) acp *= omb[i];
    sacp[t] = (float)sqrt(acp);
    s1m[t]  = (float)sqrt(1.0 - acp);
  }
  if (t >= 128 && t < 128 + ITERS) {
    int k = t - 128;
    unsigned o0, o1;
    tf2x32(0u, 42u, 0u, (unsigned)k, o0, o1);
    keys[2*k] = o0; keys[2*k+1] = o1;
  }
}

// ---- kernel 2: build Bpack MFMA B-fragments --------------------------------
// B-row K-encoding per candidate c: word w=2d,2d+1 = pack(hi_d, lo_d) d=0..5;
// word 12 = pack of split(-dsq/2); 13..15 = 0.
__global__ __launch_bounds__(256) void k_prep(
    const float* __restrict__ data, uint4* __restrict__ Bpack) {
  int p = blockIdx.x * 256 + threadIdx.x;  // 0..131071
  int b = p >> 10, c = p & 1023;
  const float* dp = data + (size_t)p * 6;
  float d0 = dp[0], d1 = dp[1], d2 = dp[2], d3 = dp[3], d4 = dp[4], d5 = dp[5];
  float dsq = d0*d0;
  dsq = fmaf(d1, d1, dsq); dsq = fmaf(d2, d2, dsq);
  dsq = fmaf(d3, d3, dsq); dsq = fmaf(d4, d4, dsq); dsq = fmaf(d5, d5, dsq);
  unsigned wds[13];
  float dd[6] = {d0, d1, d2, d3, d4, d5};
#pragma unroll
  for (int d = 0; d < 6; ++d) {
    unsigned short hi, lo; split16(dd[d], hi, lo);
    unsigned pk = pack2(hi, lo);
    wds[2*d] = pk; wds[2*d+1] = pk;
  }
  {
    unsigned short hi, lo; split16(-0.5f * dsq, hi, lo);
    wds[12] = pack2(hi, lo);
  }
  int ct = c >> 4, c15 = c & 15;
  uint4* dst = Bpack + ((size_t)(b * 64 + ct)) * 64;
#pragma unroll
  for (int q = 0; q < 4; ++q) {
    uint4 v;
    v.x = (q*4+0 < 13) ? wds[q*4+0] : 0u;
    v.y = (q*4+1 < 13) ? wds[q*4+1] : 0u;
    v.z = (q*4+2 < 13) ? wds[q*4+2] : 0u;
    v.w = (q*4+3 < 13) ? wds[q*4+3] : 0u;
    dst[q * 16 + c15] = v;
  }
}

// ---- kernel 3: bias = c@Wc + (t/T)*Wt + b1 (ctx via LDS) + weight pack -----
__global__ __launch_bounds__(256) void k_biaspack(
    const float* __restrict__ ctx, const float* __restrict__ Wc,
    const float* __restrict__ Wt, const float* __restrict__ b1,
    const int* __restrict__ ts, float* __restrict__ biasb,
    const float* __restrict__ W1, const float* __restrict__ W2,
    float4* __restrict__ PA, float4* __restrict__ PB, float* __restrict__ PC) {
  if (blockIdx.x == 256) {
    for (int j = threadIdx.x; j < HID; j += 256) {
      PA[j] = make_float4(W1[j], W1[512 + j], W1[1024 + j], W1[1536 + j]);
      PB[j] = make_float4(W1[2048 + j], W1[2560 + j], W2[j*6 + 3], W2[j*6 + 4]);
      PC[j] = W2[j*6 + 5];
    }
    return;
  }
  __shared__ float sc[CTX];
  int b = blockIdx.x >> 1;
  int j = (blockIdx.x & 1) * 256 + (int)threadIdx.x;
  if (threadIdx.x < CTX) sc[threadIdx.x] = ctx[(size_t)b * CTX + threadIdx.x];
  __syncthreads();
  float acc = 0.f;
  for (int q = 0; q < CTX; ++q) acc = fmaf(sc[q], Wc[q * HID + j], acc);
  float temb = (float)ts[b] / 100.0f;
  biasb[b * HID + j] = acc + temb * Wt[j] + b1[j];
}

// ---- kernel 4: MEGA — all 8 renoise iterations, 1 block = 1 batch ----------
// 1024 threads = 16 waves; survivor-proportional tile-passes of 32 queries
// (2 M-tiles); B-panel ping-pong 4 x 16 KiB through LDS; survivor lists,
// query state (fdat), mask in LDS. Speculative cont: per-iter counts ->
// cntg[k][b] (plain store), per-point renoise bitmask -> maskg; k_final
// applies the first-failing-iteration gate exactly.
__global__ __launch_bounds__(1024, 4) void k_mega(
    const float* __restrict__ data, const float* __restrict__ noise0,
    const int* __restrict__ ts, const float* __restrict__ sacp,
    const float* __restrict__ s1m, const unsigned* __restrict__ keys,
    unsigned* __restrict__ cntg, unsigned char* __restrict__ maskg,
    const uint4* __restrict__ Bpack) {
  __shared__ uint4 stageb[2][1024];         // 32 KiB
  __shared__ float fdat[1024][6];           // 24 KiB: d0..d2, noisy3..5
  __shared__ unsigned short slist[2][1024]; // 4 KiB
  __shared__ unsigned char lmask[1024];     // 1 KiB
  __shared__ unsigned nmisA[ITERS];
  const int b = blockIdx.x;
  const int tid = (int)threadIdx.x;
  const int wv = tid >> 6, lane = tid & 63;
  const int c15 = lane & 15, quad = lane >> 4;
  const int t = ts[b];
  const float aa = sacp[t], ssv = s1m[t];
  {
    int p = (b << 10) + tid;
    const float* dp = data + (size_t)p * 6;
    const float* np0 = noise0 + (size_t)p * 6;
    fdat[tid][0] = dp[0]; fdat[tid][1] = dp[1]; fdat[tid][2] = dp[2];
    fdat[tid][3] = __fadd_rn(__fmul_rn(aa, dp[3]), __fmul_rn(ssv, np0[3]));
    fdat[tid][4] = __fadd_rn(__fmul_rn(aa, dp[4]), __fmul_rn(ssv, np0[4]));
    fdat[tid][5] = __fadd_rn(__fmul_rn(aa, dp[5]), __fmul_rn(ssv, np0[5]));
    slist[0][tid] = (unsigned short)tid;
    lmask[tid] = 0;
    if (tid < ITERS) nmisA[tid] = 0u;
  }
  const uint4* Bsrc = Bpack + (size_t)b * 4096;
  int cb = NS, par = 0;
  __syncthreads();
  for (int k = 0; k < ITERS; ++k) {
    if (cb > 0) {  // uniform across block
      unsigned kk0 = keys[2*k], kk1 = keys[2*k+1];
      int ntp = (cb + 31) >> 5;
      half8 af[2][2];
      float bv[2][2][4];
      int   bt[2][2][4];
#pragma unroll
      for (int u = 0; u < 2; ++u) {
        int tp = wv + u * 16;
#pragma unroll
        for (int m2 = 0; m2 < 2; ++m2) {
#pragma unroll
          for (int r = 0; r < 4; ++r) { bv[u][m2][r] = -__builtin_inff(); bt[u][m2][r] = 0; }
          uint4 wds = make_uint4(0u, 0u, 0u, 0u);
          if (tp < ntp) {
            int ipos = tp * 32 + m2 * 16 + c15;
            int q = (ipos < cb) ? (int)slist[par][ipos] : 0;
            if (quad < 3) {  // quad holds dims {2*quad, 2*quad+1}
              float f0 = fdat[q][quad*2], f1 = fdat[q][quad*2+1];
              unsigned short h, l;
              split16(f0, h, l); wds.x = pack2(h, h); wds.y = pack2(l, l);
              split16(f1, h, l); wds.z = pack2(h, h); wds.w = pack2(l, l);
            } else {
              wds.x = 0x3C003C00u;  // word12 = ones (dsq slot), 13..15 zero
            }
          }
          af[u][m2] = __builtin_bit_cast(half8, wds);
        }
      }
      stageb[0][tid] = Bsrc[tid];  // chunk 0
      __syncthreads();
      for (int h = 0; h < 4; ++h) {
        uint4 pre;
        if (h < 3) pre = Bsrc[(h + 1) * 1024 + tid];
        const uint4* lbuf = stageb[h & 1];
#pragma unroll
        for (int u = 0; u < 2; ++u) {
          int tp = wv + u * 16;
          if (tp >= ntp) continue;  // wave-uniform
#pragma unroll 4
          for (int ct = 0; ct < 16; ++ct) {
            half8 bf = __builtin_bit_cast(half8, lbuf[ct * 64 + lane]);
            int ctg = h * 16 + ct;
            f32x4 z = {0.f, 0.f, 0.f, 0.f};
#pragma unroll
            for (int m2 = 0; m2 < 2; ++m2) {
              f32x4 acc = __builtin_amdgcn_mfma_f32_16x16x32_f16(af[u][m2], bf, z, 0, 0, 0);
#pragma unroll
              for (int r = 0; r < 4; ++r) {
                if (acc[r] > bv[u][m2][r]) { bv[u][m2][r] = acc[r]; bt[u][m2][r] = ctg; }
              }
            }
          }
        }
        if (h < 3) { stageb[(h + 1) & 1][tid] = pre; __syncthreads(); }
      }
      // cross-col butterfly argmax (ties -> smaller candidate index)
      int bc[2][2][4];
#pragma unroll
      for (int u = 0; u < 2; ++u)
#pragma unroll
        for (int m2 = 0; m2 < 2; ++m2)
#pragma unroll
          for (int r = 0; r < 4; ++r) bc[u][m2][r] = bt[u][m2][r] * 16 + c15;
#pragma unroll
      for (int m = 1; m < 16; m <<= 1) {
#pragma unroll
        for (int u = 0; u < 2; ++u)
#pragma unroll
          for (int m2 = 0; m2 < 2; ++m2)
#pragma unroll
            for (int r = 0; r < 4; ++r) {
              float ov = __shfl_xor(bv[u][m2][r], m);
              int   oc = __shfl_xor(bc[u][m2][r], m);
              bool tk = (ov > bv[u][m2][r]) || (ov == bv[u][m2][r] && oc < bc[u][m2][r]);
              if (tk) { bv[u][m2][r] = ov; bc[u][m2][r] = oc; }
            }
      }
      // writers: 4 ballots, ONE LDS atomic per wave; survivors renoise fdat
      int rr = c15;
      unsigned long long wmk[2][2];
      unsigned cwv[2][2];
      bool mmv[2][2]; int nv[2][2];
      unsigned tot = 0u;
#pragma unroll
      for (int u = 0; u < 2; ++u)
#pragma unroll
        for (int m2 = 0; m2 < 2; ++m2) {
          bool mm = false; int n = 0;
          int tp = wv + u * 16;
          if (tp < ntp && rr < 4) {
            int opos = tp * 32 + m2 * 16 + quad * 4 + rr;
            if (opos < cb) {
              n = (int)slist[par][opos];
              int bestc = (rr == 0) ? bc[u][m2][0] : (rr == 1) ? bc[u][m2][1]
                        : (rr == 2) ? bc[u][m2][2] : bc[u][m2][3];
              mm = (bestc != n);
            }
          }
          wmk[u][m2] = __ballot(mm ? 1 : 0);
          cwv[u][m2] = (unsigned)__popcll(wmk[u][m2]);
          mmv[u][m2] = mm; nv[u][m2] = n;
          tot += cwv[u][m2];
        }
      if (tot != 0u) {  // wave-uniform
        unsigned basev = 0u;
        if (lane == 0) basev = atomicAdd(&nmisA[k], tot);
        basev = (unsigned)__shfl((int)basev, 0);
        unsigned pref = 0u;
#pragma unroll
        for (int u = 0; u < 2; ++u)
#pragma unroll
          for (int m2 = 0; m2 < 2; ++m2) {
            if (mmv[u][m2]) {
              int n = nv[u][m2];
              int pos = (int)(basev + pref) +
                        __popcll(wmk[u][m2] & ((1ull << lane) - 1ull));
              slist[par ^ 1][pos] = (unsigned short)n;
              int p = (b << 10) + n;
              unsigned base6 = (unsigned)p * 6u;
              const float* dpp = data + (size_t)p * 6;
              float z3 = nrm_from_idx(kk0, kk1, base6 + 3u);
              float z4 = nrm_from_idx(kk0, kk1, base6 + 4u);
              float z5 = nrm_from_idx(kk0, kk1, base6 + 5u);
              fdat[n][3] = __fadd_rn(__fmul_rn(aa, dpp[3]), __fmul_rn(ssv, z3));
              fdat[n][4] = __fadd_rn(__fmul_rn(aa, dpp[4]), __fmul_rn(ssv, z4));
              fdat[n][5] = __fadd_rn(__fmul_rn(aa, dpp[5]), __fmul_rn(ssv, z5));
              lmask[n] |= (unsigned char)(1u << k);
            }
            pref += cwv[u][m2];
          }
      }
      __syncthreads();
      cb = (int)nmisA[k];
      par ^= 1;
    }
  }
  maskg[(b << 10) + tid] = lmask[tid];
  if (tid < ITERS) cntg[tid * 128 + b] = nmisA[tid];
}

// ---- kernel 5: finalize — exact cont gate + noise materialization ----------
__global__ __launch_bounds__(256) void k_final(
    const float* __restrict__ data, const float* __restrict__ noise0,
    const int* __restrict__ ts, const float* __restrict__ sacp,
    const float* __restrict__ s1m, const unsigned* __restrict__ keys,
    const unsigned* __restrict__ cntg, const unsigned char* __restrict__ maskg,
    float* __restrict__ noise_f, float* __restrict__ noisy_f) {
  __shared__ int ksh;
  int tid = (int)threadIdx.x;
  if (tid < 64) {
    int ks = ITERS;
    for (int k2 = 0; k2 < ITERS; ++k2) {
      unsigned v = cntg[k2 * 128 + tid] + cntg[k2 * 128 + 64 + tid];
#pragma unroll
      for (int m = 32; m >= 1; m >>= 1) v += (unsigned)__shfl_xor((int)v, m);
      if (v < 10u && ks == ITERS) ks = k2;  // first failing iteration
    }
    if (tid == 0) ksh = ks;
  }
  __syncthreads();
  int kstar = ksh;
  unsigned gate = (kstar >= ITERS) ? 0xFFu : ((1u << kstar) - 1u);
  int p = (int)blockIdx.x * 256 + tid;
  int b = p >> 10;
  int t = ts[b];
  float aa = sacp[t], ssv = s1m[t];
  unsigned m = (unsigned)maskg[p] & gate;
  float z3, z4, z5;
  if (m) {
    int j = 31 - __clz((int)m);  // last applied renoise iteration
    unsigned base6 = (unsigned)p * 6u;
    unsigned kk0 = keys[2*j], kk1 = keys[2*j+1];
    z3 = nrm_from_idx(kk0, kk1, base6 + 3u);
    z4 = nrm_from_idx(kk0, kk1, base6 + 4u);
    z5 = nrm_from_idx(kk0, kk1, base6 + 5u);
  } else {
    const float* np0 = noise0 + (size_t)p * 6;
    z3 = np0[3]; z4 = np0[4]; z5 = np0[5];
  }
  const float* dp = data + (size_t)p * 6;
  noise_f[p*3+0] = z3; noise_f[p*3+1] = z4; noise_f[p*3+2] = z5;
  noisy_f[p*3+0] = __fadd_rn(__fmul_rn(aa, dp[3]), __fmul_rn(ssv, z3));
  noisy_f[p*3+1] = __fadd_rn(__fmul_rn(aa, dp[4]), __fmul_rn(ssv, z4));
  noisy_f[p*3+2] = __fadd_rn(__fmul_rn(aa, dp[5]), __fmul_rn(ssv, z5));
}

// ---- kernel 6: conditional MLP + masked SE partial (weights via LDS) -------
__global__ __launch_bounds__(256) void k_loss(
    const float* __restrict__ data, const float* __restrict__ noise_f,
    const float* __restrict__ noisy_f, const float* __restrict__ biasb,
    const float4* __restrict__ PA, const float4* __restrict__ PB,
    const float* __restrict__ PC, const float* __restrict__ b2,
    float* __restrict__ part) {
  __shared__ float4 sA[HID];
  __shared__ float4 sB[HID];
  __shared__ float  sC[HID];
  __shared__ float  sb[HID];
  int b = blockIdx.x >> 2, qq = blockIdx.x & 3;
  int tid = (int)threadIdx.x;
  for (int j = tid; j < HID; j += 256) {
    sA[j] = PA[j]; sB[j] = PB[j]; sC[j] = PC[j];
    sb[j] = biasb[(size_t)b * HID + j];
  }
  __syncthreads();
  int p = (b << 10) + qq * 256 + tid;
  float x0 = data[p*6+0], x1 = data[p*6+1], x2 = data[p*6+2];
  float x3 = noisy_f[p*3+0], x4 = noisy_f[p*3+1], x5 = noisy_f[p*3+2];
  float a0 = 0.f, a1 = 0.f, a2 = 0.f;
#pragma unroll 4
  for (int j = 0; j < HID; ++j) {
    float4 A = sA[j];
    float4 Bv = sB[j];
    float s = x0 * A.x;
    s = fmaf(x1, A.y, s); s = fmaf(x2, A.z, s);
    s = fmaf(x3, A.w, s); s = fmaf(x4, Bv.x, s); s = fmaf(x5, Bv.y, s);
    s += sb[j];
    float h = ftanh(s);
    a0 = fmaf(h, Bv.z, a0);
    a1 = fmaf(h, Bv.w, a1);
    a2 = fmaf(h, sC[j], a2);
  }
  float d0 = (a0 + b2[3]) - noise_f[p*3+0];
  float d1 = (a1 + b2[4]) - noise_f[p*3+1];
  float d2 = (a2 + b2[5]) - noise_f[p*3+2];
  float lsum = d0*d0;
  lsum = fmaf(d1, d1, lsum);
  lsum = fmaf(d2, d2, lsum);
#pragma unroll
  for (int off = 32; off > 0; off >>= 1) lsum += __shfl_down(lsum, off);
  __shared__ float red[4];
  if ((tid & 63) == 0) red[tid >> 6] = lsum;
  __syncthreads();
  if (tid == 0) part[blockIdx.x] = red[0] + red[1] + red[2] + red[3];
}

// ---- kernel 7: final reduce ------------------------------------------------
__global__ void k_red(const float* __restrict__ part, float* __restrict__ out) {
  int b = (int)threadIdx.x;
  if (b < BS) {
    out[b] = (part[4*b] + part[4*b+1] + part[4*b+2] + part[4*b+3]) / 3072.0f;
  }
}

// ---------------------------------------------------------------------------
extern "C" void kernel_launch(void* const* d_in, const int* in_sizes, int n_in,
                              void* d_out, int out_size, void* d_ws, size_t ws_size,
                              hipStream_t stream) {
  (void)in_sizes; (void)n_in; (void)out_size; (void)ws_size;
  const float* data    = (const float*)d_in[0];
  const float* context = (const float*)d_in[1];
  const float* noise0  = (const float*)d_in[2];
  const float* W1      = (const float*)d_in[3];
  const float* Wc      = (const float*)d_in[4];
  const float* Wt      = (const float*)d_in[5];
  const float* b1      = (const float*)d_in[6];
  const float* W2      = (const float*)d_in[7];
  const float* b2      = (const float*)d_in[8];
  const int*   ts      = (const int*)d_in[9];
  float* out = (float*)d_out;

  char* w = (char*)d_ws;
  float*    sacp   = (float*)(w + OFF_SACP);
  float*    s1m    = (float*)(w + OFF_S1M);
  unsigned* keys   = (unsigned*)(w + OFF_KEYS);
  unsigned* cntg   = (unsigned*)(w + OFF_CNTG);
  unsigned char* maskg = (unsigned char*)(w + OFF_MASK);
  uint4*    Bpack  = (uint4*)(w + OFF_BPACK);
  float*    noisef = (float*)(w + OFF_NOISE);
  float*    noisyf = (float*)(w + OFF_NOISY);
  float*    biasb  = (float*)(w + OFF_BIAS);
  float4*   PA     = (float4*)(w + OFF_PA);
  float4*   PB     = (float4*)(w + OFF_PB);
  float*    PC     = (float*)(w + OFF_PC);
  float*    part   = (float*)(w + OFF_PART);

  k_init<<<1, 256, 0, stream>>>(sacp, s1m, keys);
  k_biaspack<<<257, 256, 0, stream>>>(context, Wc, Wt, b1, ts, biasb,
                                      W1, W2, PA, PB, PC);
  k_prep<<<512, 256, 0, stream>>>(data, Bpack);
  k_mega<<<128, 1024, 0, stream>>>(data, noise0, ts, sacp, s1m, keys,
                                   cntg, maskg, Bpack);
  k_final<<<512, 256, 0, stream>>>(data, noise0, ts, sacp, s1m, keys,
                                   cntg, maskg, noisef, noisyf);
  k_loss<<<512, 256, 0, stream>>>(data, noisef, noisyf, biasb, PA, PB, PC, b2, part);
  k_red<<<1, 128, 0, stream>>>(part, out);
}

// Round 7
// 216.253 us; speedup vs baseline: 1.9447x; 1.9447x over previous
//
#include <hip/hip_runtime.h>
#include <hip/hip_bf16.h>
#include <hip/hip_fp16.h>
#include <math.h>

// ---------------------------------------------------------------------------
// Diffusion renoise-loop + conditional MLP loss, MI355X (gfx950).
// RNG: threefry_partitionable (bit-exact, absmax 0.0 rounds 1-6).
// Round 7: match test via rowmax==diag (no argmax-index tracking: 4 v_max vs
// 12 cmp/sel per MFMA), diag from a gathered-B MFMA (bit-identical), 512
// blocks x 4 waves (3 blocks/CU), distributed renoise, speculative cont.
#define BS   128
#define NS   1024
#define HID  512
#define CTX  128
#define TT   100
#define ITERS 8

// ---- workspace layout (bytes) ---------------------------------------------
constexpr size_t OFF_SACP  = 0;         // 100 f32
constexpr size_t OFF_S1M   = 512;       // 100 f32
constexpr size_t OFF_KEYS  = 1024;      // 16 u32
constexpr size_t OFF_CNTG  = 1152;      // u32[8][512] -> 17536
constexpr size_t OFF_MASK  = 17536;     // u8[131072] -> 148608
constexpr size_t OFF_BPACK = 262144;    // uint4[128*64*64] = 8 MiB -> 8650752
constexpr size_t OFF_NOISE = 8650752;   // f32[128*1024*3] -> 10223616
constexpr size_t OFF_NOISY = 10223616;  // f32[128*1024*3] -> 11796480
constexpr size_t OFF_BIAS  = 11796480;  // f32[128*512] -> 12058624
constexpr size_t OFF_PA    = 12058624;  // float4[512] -> 12066816
constexpr size_t OFF_PB    = 12066816;  // float4[512] -> 12075008
constexpr size_t OFF_PC    = 12075008;  // f32[512]   -> 12077056
constexpr size_t OFF_PART  = 12077056;  // f32[512]   -> 12079104 (~12.1 MB)

typedef __attribute__((ext_vector_type(8))) _Float16 half8;
typedef __attribute__((ext_vector_type(4))) float f32x4;

// ---- threefry2x32-20 -------------------------------------------------------
__device__ __forceinline__ unsigned rotl32(unsigned x, int r) {
  return (x << r) | (x >> (32 - r));
}
__device__ __forceinline__ void tf2x32(unsigned k0, unsigned k1,
                                       unsigned x0, unsigned x1,
                                       unsigned& o0, unsigned& o1) {
  unsigned k2 = k0 ^ k1 ^ 0x1BD11BDAu;
  x0 += k0; x1 += k1;
#define TF_R4(a,b,c,d) \
  x0 += x1; x1 = rotl32(x1,(a)); x1 ^= x0; \
  x0 += x1; x1 = rotl32(x1,(b)); x1 ^= x0; \
  x0 += x1; x1 = rotl32(x1,(c)); x1 ^= x0; \
  x0 += x1; x1 = rotl32(x1,(d)); x1 ^= x0;
  TF_R4(13,15,26,6)   x0 += k1; x1 += k2 + 1u;
  TF_R4(17,29,16,24)  x0 += k2; x1 += k0 + 2u;
  TF_R4(13,15,26,6)   x0 += k0; x1 += k1 + 3u;
  TF_R4(17,29,16,24)  x0 += k1; x1 += k2 + 4u;
  TF_R4(13,15,26,6)   x0 += k2; x1 += k0 + 5u;
#undef TF_R4
  o0 = x0; o1 = x1;
}

__device__ __forceinline__ float bits_to_u(unsigned bits) {
  float f = __uint_as_float((bits >> 9) | 0x3f800000u) - 1.0f;
  float u = f * 2.0f + (-0.99999994f);
  return fmaxf(-0.99999994f, u);
}

__device__ __forceinline__ float nrm_from_idx(unsigned k0, unsigned k1, unsigned idx) {
  unsigned o0, o1;
  tf2x32(k0, k1, 0u, idx, o0, o1);
  return 1.41421356f * erfinvf(bits_to_u(o0 ^ o1));
}

__device__ __forceinline__ float ftanh(float x) {
  float e = __expf(2.0f * x);
  float r = __builtin_amdgcn_rcpf(e + 1.0f);
  return fmaf(-2.0f, r, 1.0f);
}

// fp16 hi/lo split: x ~= hi + lo with |err| <~ 2^-23 |x|
__device__ __forceinline__ void split16(float x, unsigned short& hi, unsigned short& lo) {
  __half h = __float2half(x);
  float hf = __half2float(h);
  __half l = __float2half(x - hf);
  hi = __half_as_ushort(h);
  lo = __half_as_ushort(l);
}
__device__ __forceinline__ unsigned pack2(unsigned short a, unsigned short b) {
  return (unsigned)a | ((unsigned)b << 16);
}

// ---- kernel 1: tables + iteration keys -------------------------------------
__global__ void k_init(float* __restrict__ sacp, float* __restrict__ s1m,
                       unsigned* __restrict__ keys) {
  __shared__ double omb[TT];
  int t = threadIdx.x;
  if (t < TT) {
    const double PI = 3.14159265358979323846;
    double t0 = (double)t / TT, t1 = (double)(t + 1) / TT;
    double c0 = cos((t0 + 0.008) / 1.008 * PI * 0.5); double ab0 = c0 * c0;
    double c1 = cos((t1 + 0.008) / 1.008 * PI * 0.5); double ab1 = c1 * c1;
    double beta = 1.0 - ab1 / ab0;
    if (beta > 0.999) beta = 0.999;
    omb[t] = 1.0 - beta;
  }
  __syncthreads();
  if (t < TT) {
    double acp = 1.0;
    for (int i = 0; i <= t; ++i) acp *= omb[i];
    sacp[t] = (float)sqrt(acp);
    s1m[t]  = (float)sqrt(1.0 - acp);
  }
  if (t >= 128 && t < 128 + ITERS) {
    int k = t - 128;
    unsigned o0, o1;
    tf2x32(0u, 42u, 0u, (unsigned)k, o0, o1);
    keys[2*k] = o0; keys[2*k+1] = o1;
  }
}

// ---- kernel 2: build Bpack MFMA B-fragments --------------------------------
// Row n=(ct*16+c15) of batch b: qword q at Bpack[b*4096 + ct*64 + q*16 + c15].
// K-encoding: words 2d,2d+1 = pack(hi_d, lo_d) d=0..5; word12 = split(-dsq/2).
__global__ __launch_bounds__(256) void k_prep(
    const float* __restrict__ data, uint4* __restrict__ Bpack) {
  int p = blockIdx.x * 256 + threadIdx.x;  // 0..131071
  int b = p >> 10, c = p & 1023;
  const float* dp = data + (size_t)p * 6;
  float d0 = dp[0], d1 = dp[1], d2 = dp[2], d3 = dp[3], d4 = dp[4], d5 = dp[5];
  float dsq = d0*d0;
  dsq = fmaf(d1, d1, dsq); dsq = fmaf(d2, d2, dsq);
  dsq = fmaf(d3, d3, dsq); dsq = fmaf(d4, d4, dsq); dsq = fmaf(d5, d5, dsq);
  unsigned wds[13];
  float dd[6] = {d0, d1, d2, d3, d4, d5};
#pragma unroll
  for (int d = 0; d < 6; ++d) {
    unsigned short hi, lo; split16(dd[d], hi, lo);
    unsigned pk = pack2(hi, lo);
    wds[2*d] = pk; wds[2*d+1] = pk;
  }
  {
    unsigned short hi, lo; split16(-0.5f * dsq, hi, lo);
    wds[12] = pack2(hi, lo);
  }
  int ct = c >> 4, c15 = c & 15;
  uint4* dst = Bpack + ((size_t)(b * 64 + ct)) * 64;
#pragma unroll
  for (int q = 0; q < 4; ++q) {
    uint4 v;
    v.x = (q*4+0 < 13) ? wds[q*4+0] : 0u;
    v.y = (q*4+1 < 13) ? wds[q*4+1] : 0u;
    v.z = (q*4+2 < 13) ? wds[q*4+2] : 0u;
    v.w = (q*4+3 < 13) ? wds[q*4+3] : 0u;
    dst[q * 16 + c15] = v;
  }
}

// ---- kernel 3: bias = c@Wc + (t/T)*Wt + b1 (ctx via LDS) + weight pack -----
__global__ __launch_bounds__(256) void k_biaspack(
    const float* __restrict__ ctx, const float* __restrict__ Wc,
    const float* __restrict__ Wt, const float* __restrict__ b1,
    const int* __restrict__ ts, float* __restrict__ biasb,
    const float* __restrict__ W1, const float* __restrict__ W2,
    float4* __restrict__ PA, float4* __restrict__ PB, float* __restrict__ PC) {
  if (blockIdx.x == 256) {
    for (int j = threadIdx.x; j < HID; j += 256) {
      PA[j] = make_float4(W1[j], W1[512 + j], W1[1024 + j], W1[1536 + j]);
      PB[j] = make_float4(W1[2048 + j], W1[2560 + j], W2[j*6 + 3], W2[j*6 + 4]);
      PC[j] = W2[j*6 + 5];
    }
    return;
  }
  __shared__ float sc[CTX];
  int b = blockIdx.x >> 1;
  int j = (blockIdx.x & 1) * 256 + (int)threadIdx.x;
  if (threadIdx.x < CTX) sc[threadIdx.x] = ctx[(size_t)b * CTX + threadIdx.x];
  __syncthreads();
  float acc = 0.f;
  for (int q = 0; q < CTX; ++q) acc = fmaf(sc[q], Wc[q * HID + j], acc);
  float temb = (float)ts[b] / 100.0f;
  biasb[b * HID + j] = acc + temb * Wt[j] + b1[j];
}

// ---- kernel 4: renoise loop — 512 blocks (4 q-slices x 128 batches) --------
// Block: 4 waves x 256 queries (local slice). All 8 iterations in-kernel.
// Match test: rowmax(score) == diag, diag via gathered-B MFMA (bit-identical
// column values). B-panel ping-pong 4 x 16 KiB. Speculative cont + k_final.
__global__ __launch_bounds__(256, 3) void k_renoise(
    const float* __restrict__ data, const float* __restrict__ noise0,
    const int* __restrict__ ts, const float* __restrict__ sacp,
    const float* __restrict__ s1m, const unsigned* __restrict__ keys,
    unsigned* __restrict__ cntg, unsigned char* __restrict__ maskg,
    const uint4* __restrict__ Bpack) {
  __shared__ uint4 stageb[2][1024];          // 32 KB
  __shared__ float fdat[256][6];             // 6 KB
  __shared__ unsigned short slist[2][256];   // 1 KB
  __shared__ float sdiag[4][64];             // 1 KB
  __shared__ unsigned char lmask[256];
  __shared__ unsigned nmis[ITERS];
  const int b = blockIdx.x & 127, qb = blockIdx.x >> 7;
  const int tid = (int)threadIdx.x;
  const int wv = tid >> 6, lane = tid & 63;
  const int c15 = lane & 15, quad = lane >> 4;
  const int n0 = qb * 256;
  const int t = ts[b];
  const float aa = sacp[t], ssv = s1m[t];
  {
    int p = (b << 10) + n0 + tid;
    const float* dp = data + (size_t)p * 6;
    const float* np0 = noise0 + (size_t)p * 6;
    fdat[tid][0] = dp[0]; fdat[tid][1] = dp[1]; fdat[tid][2] = dp[2];
    fdat[tid][3] = __fadd_rn(__fmul_rn(aa, dp[3]), __fmul_rn(ssv, np0[3]));
    fdat[tid][4] = __fadd_rn(__fmul_rn(aa, dp[4]), __fmul_rn(ssv, np0[4]));
    fdat[tid][5] = __fadd_rn(__fmul_rn(aa, dp[5]), __fmul_rn(ssv, np0[5]));
    slist[0][tid] = (unsigned short)tid;
    lmask[tid] = 0;
    if (tid < ITERS) nmis[tid] = 0u;
  }
  const uint4* Bsrc = Bpack + (size_t)b * 4096;
  int cbl = 256, par = 0;
  __syncthreads();
  for (int k = 0; k < ITERS && cbl > 0; ++k) {
    int ntl = (cbl + 15) >> 4;  // local M-tiles (<=16)
    // ---- A-fragments (tile tt = wv + j*4) + gathered-B for diag ------------
    half8 af[4];
    uint4 bg[4];
#pragma unroll
    for (int j = 0; j < 4; ++j) {
      int tt = wv + j * 4;
      int pos = tt * 16 + c15;
      bool ract = (tt < ntl) && (pos < cbl);
      int l = ract ? (int)slist[par][pos] : 0;
      uint4 wds = make_uint4(0u, 0u, 0u, 0u);
      if (ract) {
        if (quad < 3) {
          unsigned short h, lo2;
          float f0 = fdat[l][quad*2], f1 = fdat[l][quad*2+1];
          split16(f0, h, lo2); wds.x = pack2(h, h); wds.y = pack2(lo2, lo2);
          split16(f1, h, lo2); wds.z = pack2(h, h); wds.w = pack2(lo2, lo2);
        } else {
          wds.x = 0x3C003C00u;  // ones in the dsq slot
        }
      }
      af[j] = __builtin_bit_cast(half8, wds);
      int nrow = n0 + l;  // gathered-B: column c15 = panel row of n_{c15}
      bg[j] = Bsrc[(nrow >> 4) * 64 + quad * 16 + (nrow & 15)];
    }
    // ---- diag MFMAs (column-position-independent => bit-identical) ---------
#pragma unroll
    for (int j = 0; j < 4; ++j) {
      f32x4 z = {0.f, 0.f, 0.f, 0.f};
      f32x4 dacc = __builtin_amdgcn_mfma_f32_16x16x32_f16(
          af[j], __builtin_bit_cast(half8, bg[j]), z, 0, 0, 0);
      if ((c15 >> 2) == quad) sdiag[wv][j * 16 + c15] = dacc[c15 & 3];
    }
    // ---- stage chunk 0 -----------------------------------------------------
#pragma unroll
    for (int j2 = 0; j2 < 4; ++j2) stageb[0][j2 * 256 + tid] = Bsrc[j2 * 256 + tid];
    __syncthreads();
    // ---- sweep: rowmax only (4 v_max per MFMA) -----------------------------
    float bv[4][4];
#pragma unroll
    for (int j = 0; j < 4; ++j)
#pragma unroll
      for (int r = 0; r < 4; ++r) bv[j][r] = -__builtin_inff();
    for (int h = 0; h < 4; ++h) {
      uint4 pre[4];
      if (h < 3) {
#pragma unroll
        for (int j2 = 0; j2 < 4; ++j2)
          pre[j2] = Bsrc[(h + 1) * 1024 + j2 * 256 + tid];
      }
      const uint4* lbuf = stageb[h & 1];
#pragma unroll 4
      for (int ct = 0; ct < 16; ++ct) {
        half8 bf = __builtin_bit_cast(half8, lbuf[ct * 64 + lane]);
        f32x4 z = {0.f, 0.f, 0.f, 0.f};
#pragma unroll
        for (int j = 0; j < 4; ++j) {
          f32x4 acc = __builtin_amdgcn_mfma_f32_16x16x32_f16(af[j], bf, z, 0, 0, 0);
#pragma unroll
          for (int r = 0; r < 4; ++r) bv[j][r] = fmaxf(bv[j][r], acc[r]);
        }
      }
      if (h < 3) {
#pragma unroll
        for (int j2 = 0; j2 < 4; ++j2) stageb[(h + 1) & 1][j2 * 256 + tid] = pre[j2];
        __syncthreads();
      }
    }
    // ---- butterfly max over 16 cols ---------------------------------------
#pragma unroll
    for (int m = 1; m < 16; m <<= 1)
#pragma unroll
      for (int j = 0; j < 4; ++j)
#pragma unroll
        for (int r = 0; r < 4; ++r)
          bv[j][r] = fmaxf(bv[j][r], __shfl_xor(bv[j][r], m));
    // ---- writers: mismatch = rowmax > diag; compact; 1 LDS atomic/wave ----
    int rr = c15;
    unsigned long long wmk[4];
    unsigned cwv[4];
    bool mmv[4]; int lv[4];
    unsigned tot = 0u;
#pragma unroll
    for (int j = 0; j < 4; ++j) {
      bool mm = false; int l = 0;
      if (rr < 4) {
        int tt = wv + j * 4;
        int m = quad * 4 + rr;
        int pos = tt * 16 + m;
        if (pos < cbl) {
          l = (int)slist[par][pos];
          mm = bv[j][rr] > sdiag[wv][j * 16 + m];
        }
      }
      wmk[j] = __ballot(mm ? 1 : 0);
      cwv[j] = (unsigned)__popcll(wmk[j]);
      mmv[j] = mm; lv[j] = l;
      tot += cwv[j];
    }
    if (tot != 0u) {  // wave-uniform
      unsigned basev = 0u;
      if (lane == 0) basev = atomicAdd(&nmis[k], tot);
      basev = (unsigned)__shfl((int)basev, 0);
      unsigned pref = 0u;
#pragma unroll
      for (int j = 0; j < 4; ++j) {
        if (mmv[j]) {
          int pos = (int)(basev + pref) + __popcll(wmk[j] & ((1ull << lane) - 1ull));
          slist[par ^ 1][pos] = (unsigned short)lv[j];
        }
        pref += cwv[j];
      }
    }
    __syncthreads();
    int newcb = (int)nmis[k];
    // ---- distributed renoise of survivors ----------------------------------
    if (tid < newcb) {
      unsigned kk0 = keys[2*k], kk1 = keys[2*k+1];
      int l = (int)slist[par ^ 1][tid];
      int p = (b << 10) + n0 + l;
      unsigned base6 = (unsigned)p * 6u;
      float z3 = nrm_from_idx(kk0, kk1, base6 + 3u);
      float z4 = nrm_from_idx(kk0, kk1, base6 + 4u);
      float z5 = nrm_from_idx(kk0, kk1, base6 + 5u);
      const float* dpp = data + (size_t)p * 6;
      fdat[l][3] = __fadd_rn(__fmul_rn(aa, dpp[3]), __fmul_rn(ssv, z3));
      fdat[l][4] = __fadd_rn(__fmul_rn(aa, dpp[4]), __fmul_rn(ssv, z4));
      fdat[l][5] = __fadd_rn(__fmul_rn(aa, dpp[5]), __fmul_rn(ssv, z5));
      lmask[l] |= (unsigned char)(1u << k);
    }
    __syncthreads();
    par ^= 1; cbl = newcb;
  }
  maskg[(b << 10) + n0 + tid] = lmask[tid];
  if (tid < ITERS) cntg[tid * 512 + (int)blockIdx.x] = nmis[tid];
}

// ---- kernel 5: finalize — exact cont gate + noise materialization ----------
__global__ __launch_bounds__(256) void k_final(
    const float* __restrict__ data, const float* __restrict__ noise0,
    const int* __restrict__ ts, const float* __restrict__ sacp,
    const float* __restrict__ s1m, const unsigned* __restrict__ keys,
    const unsigned* __restrict__ cntg, const unsigned char* __restrict__ maskg,
    float* __restrict__ noise_f, float* __restrict__ noisy_f) {
  __shared__ int ksh;
  int tid = (int)threadIdx.x;
  if (tid < 64) {
    int ks = ITERS;
    for (int k2 = 0; k2 < ITERS; ++k2) {
      unsigned v = 0u;
#pragma unroll
      for (int i = 0; i < 8; ++i) v += cntg[k2 * 512 + i * 64 + tid];
#pragma unroll
      for (int m = 32; m >= 1; m >>= 1) v += (unsigned)__shfl_xor((int)v, m);
      if (v < 10u && ks == ITERS) ks = k2;  // first failing iteration
    }
    if (tid == 0) ksh = ks;
  }
  __syncthreads();
  int kstar = ksh;
  unsigned gate = (kstar >= ITERS) ? 0xFFu : ((1u << kstar) - 1u);
  int p = (int)blockIdx.x * 256 + tid;
  int b = p >> 10;
  int t = ts[b];
  float aa = sacp[t], ssv = s1m[t];
  unsigned m = (unsigned)maskg[p] & gate;
  float z3, z4, z5;
  if (m) {
    int j = 31 - __clz((int)m);  // last applied renoise iteration
    unsigned base6 = (unsigned)p * 6u;
    unsigned kk0 = keys[2*j], kk1 = keys[2*j+1];
    z3 = nrm_from_idx(kk0, kk1, base6 + 3u);
    z4 = nrm_from_idx(kk0, kk1, base6 + 4u);
    z5 = nrm_from_idx(kk0, kk1, base6 + 5u);
  } else {
    const float* np0 = noise0 + (size_t)p * 6;
    z3 = np0[3]; z4 = np0[4]; z5 = np0[5];
  }
  const float* dp = data + (size_t)p * 6;
  noise_f[p*3+0] = z3; noise_f[p*3+1] = z4; noise_f[p*3+2] = z5;
  noisy_f[p*3+0] = __fadd_rn(__fmul_rn(aa, dp[3]), __fmul_rn(ssv, z3));
  noisy_f[p*3+1] = __fadd_rn(__fmul_rn(aa, dp[4]), __fmul_rn(ssv, z4));
  noisy_f[p*3+2] = __fadd_rn(__fmul_rn(aa, dp[5]), __fmul_rn(ssv, z5));
}

// ---- kernel 6: conditional MLP + masked SE partial (weights via LDS) -------
__global__ __launch_bounds__(256) void k_loss(
    const float* __restrict__ data, const float* __restrict__ noise_f,
    const float* __restrict__ noisy_f, const float* __restrict__ biasb,
    const float4* __restrict__ PA, const float4* __restrict__ PB,
    const float* __restrict__ PC, const float* __restrict__ b2,
    float* __restrict__ part) {
  __shared__ float4 sA[HID];
  __shared__ float4 sB[HID];
  __shared__ float  sC[HID];
  __shared__ float  sb[HID];
  int b = blockIdx.x >> 2, qq = blockIdx.x & 3;
  int tid = (int)threadIdx.x;
  for (int j = tid; j < HID; j += 256) {
    sA[j] = PA[j]; sB[j] = PB[j]; sC[j] = PC[j];
    sb[j] = biasb[(size_t)b * HID + j];
  }
  __syncthreads();
  int p = (b << 10) + qq * 256 + tid;
  float x0 = data[p*6+0], x1 = data[p*6+1], x2 = data[p*6+2];
  float x3 = noisy_f[p*3+0], x4 = noisy_f[p*3+1], x5 = noisy_f[p*3+2];
  float a0 = 0.f, a1 = 0.f, a2 = 0.f;
#pragma unroll 4
  for (int j = 0; j < HID; ++j) {
    float4 A = sA[j];
    float4 Bv = sB[j];
    float s = x0 * A.x;
    s = fmaf(x1, A.y, s); s = fmaf(x2, A.z, s);
    s = fmaf(x3, A.w, s); s = fmaf(x4, Bv.x, s); s = fmaf(x5, Bv.y, s);
    s += sb[j];
    float h = ftanh(s);
    a0 = fmaf(h, Bv.z, a0);
    a1 = fmaf(h, Bv.w, a1);
    a2 = fmaf(h, sC[j], a2);
  }
  float d0 = (a0 + b2[3]) - noise_f[p*3+0];
  float d1 = (a1 + b2[4]) - noise_f[p*3+1];
  float d2 = (a2 + b2[5]) - noise_f[p*3+2];
  float lsum = d0*d0;
  lsum = fmaf(d1, d1, lsum);
  lsum = fmaf(d2, d2, lsum);
#pragma unroll
  for (int off = 32; off > 0; off >>= 1) lsum += __shfl_down(lsum, off);
  __shared__ float red[4];
  if ((tid & 63) == 0) red[tid >> 6] = lsum;
  __syncthreads();
  if (tid == 0) part[blockIdx.x] = red[0] + red[1] + red[2] + red[3];
}

// ---- kernel 7: final reduce ------------------------------------------------
__global__ void k_red(const float* __restrict__ part, float* __restrict__ out) {
  int b = (int)threadIdx.x;
  if (b < BS) {
    out[b] = (part[4*b] + part[4*b+1] + part[4*b+2] + part[4*b+3]) / 3072.0f;
  }
}

// ---------------------------------------------------------------------------
extern "C" void kernel_launch(void* const* d_in, const int* in_sizes, int n_in,
                              void* d_out, int out_size, void* d_ws, size_t ws_size,
                              hipStream_t stream) {
  (void)in_sizes; (void)n_in; (void)out_size; (void)ws_size;
  const float* data    = (const float*)d_in[0];
  const float* context = (const float*)d_in[1];
  const float* noise0  = (const float*)d_in[2];
  const float* W1      = (const float*)d_in[3];
  const float* Wc      = (const float*)d_in[4];
  const float* Wt      = (const float*)d_in[5];
  const float* b1      = (const float*)d_in[6];
  const float* W2      = (const float*)d_in[7];
  const float* b2      = (const float*)d_in[8];
  const int*   ts      = (const int*)d_in[9];
  float* out = (float*)d_out;

  char* w = (char*)d_ws;
  float*    sacp   = (float*)(w + OFF_SACP);
  float*    s1m    = (float*)(w + OFF_S1M);
  unsigned* keys   = (unsigned*)(w + OFF_KEYS);
  unsigned* cntg   = (unsigned*)(w + OFF_CNTG);
  unsigned char* maskg = (unsigned char*)(w + OFF_MASK);
  uint4*    Bpack  = (uint4*)(w + OFF_BPACK);
  float*    noisef = (float*)(w + OFF_NOISE);
  float*    noisyf = (float*)(w + OFF_NOISY);
  float*    biasb  = (float*)(w + OFF_BIAS);
  float4*   PA     = (float4*)(w + OFF_PA);
  float4*   PB     = (float4*)(w + OFF_PB);
  float*    PC     = (float*)(w + OFF_PC);
  float*    part   = (float*)(w + OFF_PART);

  k_init<<<1, 256, 0, stream>>>(sacp, s1m, keys);
  k_biaspack<<<257, 256, 0, stream>>>(context, Wc, Wt, b1, ts, biasb,
                                      W1, W2, PA, PB, PC);
  k_prep<<<512, 256, 0, stream>>>(data, Bpack);
  k_renoise<<<512, 256, 0, stream>>>(data, noise0, ts, sacp, s1m, keys,
                                     cntg, maskg, Bpack);
  k_final<<<512, 256, 0, stream>>>(data, noise0, ts, sacp, s1m, keys,
                                   cntg, maskg, noisef, noisyf);
  k_loss<<<512, 256, 0, stream>>>(data, noisef, noisyf, biasb, PA, PB, PC, b2, part);
  k_red<<<1, 128, 0, stream>>>(part, out);
}

// Round 8
// 214.167 us; speedup vs baseline: 1.9636x; 1.0097x over previous
//
#include <hip/hip_runtime.h>
#include <hip/hip_bf16.h>
#include <hip/hip_fp16.h>
#include <math.h>

// ---------------------------------------------------------------------------
// Diffusion renoise-loop + conditional MLP loss, MI355X (gfx950).
// RNG: threefry_partitionable (bit-exact, absmax 0.0 rounds 1-7).
// Round 8: candidates-in-A / queries-in-B MFMA (rowmax collapses via v_max3),
// dedup 40-byte candidate records resident in LDS all 8 iterations (no
// restage, 2 barriers/iter), k_prep folded into k_renoise, k_loss j-split
// across waves (was LDS-broadcast-issue-bound ~60us).
#define BS   128
#define NS   1024
#define HID  512
#define CTX  128
#define TT   100
#define ITERS 8

// ---- workspace layout (bytes) ---------------------------------------------
constexpr size_t OFF_SACP  = 0;         // 100 f32
constexpr size_t OFF_S1M   = 512;       // 100 f32
constexpr size_t OFF_KEYS  = 1024;      // 16 u32
constexpr size_t OFF_CNTG  = 1152;      // u32[8][512] -> 17536
constexpr size_t OFF_MASK  = 17536;     // u8[131072] -> 148608
constexpr size_t OFF_NOISE = 262144;    // f32[128*1024*3] -> 1835008
constexpr size_t OFF_NOISY = 1835008;   // f32[128*1024*3] -> 3407872
constexpr size_t OFF_BIAS  = 3407872;   // f32[128*512] -> 3670016
constexpr size_t OFF_PA    = 3670016;   // float4[512] -> 3678208
constexpr size_t OFF_PB    = 3678208;   // float4[512] -> 3686400
constexpr size_t OFF_PC    = 3686400;   // f32[512]   -> 3688448
constexpr size_t OFF_PART  = 3688448;   // f32[512]   -> 3690496 (~3.7 MB)

typedef __attribute__((ext_vector_type(8))) _Float16 half8;
typedef __attribute__((ext_vector_type(4))) float f32x4;

// ---- threefry2x32-20 -------------------------------------------------------
__device__ __forceinline__ unsigned rotl32(unsigned x, int r) {
  return (x << r) | (x >> (32 - r));
}
__device__ __forceinline__ void tf2x32(unsigned k0, unsigned k1,
                                       unsigned x0, unsigned x1,
                                       unsigned& o0, unsigned& o1) {
  unsigned k2 = k0 ^ k1 ^ 0x1BD11BDAu;
  x0 += k0; x1 += k1;
#define TF_R4(a,b,c,d) \
  x0 += x1; x1 = rotl32(x1,(a)); x1 ^= x0; \
  x0 += x1; x1 = rotl32(x1,(b)); x1 ^= x0; \
  x0 += x1; x1 = rotl32(x1,(c)); x1 ^= x0; \
  x0 += x1; x1 = rotl32(x1,(d)); x1 ^= x0;
  TF_R4(13,15,26,6)   x0 += k1; x1 += k2 + 1u;
  TF_R4(17,29,16,24)  x0 += k2; x1 += k0 + 2u;
  TF_R4(13,15,26,6)   x0 += k0; x1 += k1 + 3u;
  TF_R4(17,29,16,24)  x0 += k1; x1 += k2 + 4u;
  TF_R4(13,15,26,6)   x0 += k2; x1 += k0 + 5u;
#undef TF_R4
  o0 = x0; o1 = x1;
}

__device__ __forceinline__ float bits_to_u(unsigned bits) {
  float f = __uint_as_float((bits >> 9) | 0x3f800000u) - 1.0f;
  float u = f * 2.0f + (-0.99999994f);
  return fmaxf(-0.99999994f, u);
}

__device__ __forceinline__ float nrm_from_idx(unsigned k0, unsigned k1, unsigned idx) {
  unsigned o0, o1;
  tf2x32(k0, k1, 0u, idx, o0, o1);
  return 1.41421356f * erfinvf(bits_to_u(o0 ^ o1));
}

__device__ __forceinline__ float ftanh(float x) {
  float e = __expf(2.0f * x);
  float r = __builtin_amdgcn_rcpf(e + 1.0f);
  return fmaf(-2.0f, r, 1.0f);
}

// fp16 hi/lo split: x ~= hi + lo with |err| <~ 2^-23 |x|
__device__ __forceinline__ void split16(float x, unsigned short& hi, unsigned short& lo) {
  __half h = __float2half(x);
  float hf = __half2float(h);
  __half l = __float2half(x - hf);
  hi = __half_as_ushort(h);
  lo = __half_as_ushort(l);
}
__device__ __forceinline__ unsigned pack2(unsigned short a, unsigned short b) {
  return (unsigned)a | ((unsigned)b << 16);
}

// ---- kernel 1: tables + iteration keys -------------------------------------
__global__ void k_init(float* __restrict__ sacp, float* __restrict__ s1m,
                       unsigned* __restrict__ keys) {
  __shared__ double omb[TT];
  int t = threadIdx.x;
  if (t < TT) {
    const double PI = 3.14159265358979323846;
    double t0 = (double)t / TT, t1 = (double)(t + 1) / TT;
    double c0 = cos((t0 + 0.008) / 1.008 * PI * 0.5); double ab0 = c0 * c0;
    double c1 = cos((t1 + 0.008) / 1.008 * PI * 0.5); double ab1 = c1 * c1;
    double beta = 1.0 - ab1 / ab0;
    if (beta > 0.999) beta = 0.999;
    omb[t] = 1.0 - beta;
  }
  __syncthreads();
  if (t < TT) {
    double acp = 1.0;
    for (int i = 0; i <= t; ++i) acp *= omb[i];
    sacp[t] = (float)sqrt(acp);
    s1m[t]  = (float)sqrt(1.0 - acp);
  }
  if (t >= 128 && t < 128 + ITERS) {
    int k = t - 128;
    unsigned o0, o1;
    tf2x32(0u, 42u, 0u, (unsigned)k, o0, o1);
    keys[2*k] = o0; keys[2*k+1] = o1;
  }
}

// ---- kernel 2: bias = c@Wc + (t/T)*Wt + b1 (ctx via LDS) + weight pack -----
__global__ __launch_bounds__(256) void k_biaspack(
    const float* __restrict__ ctx, const float* __restrict__ Wc,
    const float* __restrict__ Wt, const float* __restrict__ b1,
    const int* __restrict__ ts, float* __restrict__ biasb,
    const float* __restrict__ W1, const float* __restrict__ W2,
    float4* __restrict__ PA, float4* __restrict__ PB, float* __restrict__ PC) {
  if (blockIdx.x == 256) {
    for (int j = threadIdx.x; j < HID; j += 256) {
      PA[j] = make_float4(W1[j], W1[512 + j], W1[1024 + j], W1[1536 + j]);
      PB[j] = make_float4(W1[2048 + j], W1[2560 + j], W2[j*6 + 3], W2[j*6 + 4]);
      PC[j] = W2[j*6 + 5];
    }
    return;
  }
  __shared__ float sc[CTX];
  int b = blockIdx.x >> 1;
  int j = (blockIdx.x & 1) * 256 + (int)threadIdx.x;
  if (threadIdx.x < CTX) sc[threadIdx.x] = ctx[(size_t)b * CTX + threadIdx.x];
  __syncthreads();
  float acc = 0.f;
  for (int q = 0; q < CTX; ++q) acc = fmaf(sc[q], Wc[q * HID + j], acc);
  float temb = (float)ts[b] / 100.0f;
  biasb[b * HID + j] = acc + temb * Wt[j] + b1[j];
}

// ---- kernel 3: renoise loop — 512 blocks (4 q-slices x 128 batches) --------
// A = candidates (resident dedup LDS panel, 40 B/record), B = queries (regs).
// Rowmax per query collapses acc regs via v_max3; diag via gathered-A MFMA
// (bit-identical). 2 barriers/iter. Speculative cont + exact repair (k_final).
__global__ __launch_bounds__(256, 3) void k_renoise(
    const float* __restrict__ data, const float* __restrict__ noise0,
    const int* __restrict__ ts, const float* __restrict__ sacp,
    const float* __restrict__ s1m, const unsigned* __restrict__ keys,
    unsigned* __restrict__ cntg, unsigned char* __restrict__ maskg) {
  __shared__ unsigned stw[10240];            // 40 KB: 1024 records x 10 words
  __shared__ float fdat[256][6];             // 6 KB
  __shared__ unsigned short slist[2][256];   // 1 KB
  __shared__ float sdiag[4][64];             // 1 KB
  __shared__ unsigned char lmask[256];
  __shared__ unsigned nmis[ITERS];
  const int b = blockIdx.x & 127, qb = blockIdx.x >> 7;
  const int tid = (int)threadIdx.x;
  const int wv = tid >> 6, lane = tid & 63;
  const int c15 = lane & 15, quad = lane >> 4;
  const bool q3 = (quad == 3);
  const int n0 = qb * 256;
  const int t = ts[b];
  const float aa = sacp[t], ssv = s1m[t];
  // ---- init query state ----------------------------------------------------
  {
    int p = (b << 10) + n0 + tid;
    const float* dp = data + (size_t)p * 6;
    const float* np0 = noise0 + (size_t)p * 6;
    fdat[tid][0] = dp[0]; fdat[tid][1] = dp[1]; fdat[tid][2] = dp[2];
    fdat[tid][3] = __fadd_rn(__fmul_rn(aa, dp[3]), __fmul_rn(ssv, np0[3]));
    fdat[tid][4] = __fadd_rn(__fmul_rn(aa, dp[4]), __fmul_rn(ssv, np0[4]));
    fdat[tid][5] = __fadd_rn(__fmul_rn(aa, dp[5]), __fmul_rn(ssv, np0[5]));
    slist[0][tid] = (unsigned short)tid;
    lmask[tid] = 0;
    if (tid < ITERS) nmis[tid] = 0u;
  }
  // ---- build dedup candidate panel: record = [U0..U5, V, 0, pad, pad] ------
  for (int ii = 0; ii < 4; ++ii) {
    int c = ii * 256 + tid;
    const float2* dp2 = (const float2*)(data + ((size_t)(b << 10) + c) * 6);
    float2 v0 = dp2[0], v1 = dp2[1], v2 = dp2[2];
    float dd[6] = {v0.x, v0.y, v1.x, v1.y, v2.x, v2.y};
    float dsq = dd[0]*dd[0];
    dsq = fmaf(dd[1], dd[1], dsq); dsq = fmaf(dd[2], dd[2], dsq);
    dsq = fmaf(dd[3], dd[3], dsq); dsq = fmaf(dd[4], dd[4], dsq);
    dsq = fmaf(dd[5], dd[5], dsq);
    unsigned U[6];
#pragma unroll
    for (int d = 0; d < 6; ++d) {
      unsigned short hi, lo; split16(dd[d], hi, lo);
      U[d] = pack2(hi, lo);
    }
    unsigned short vh, vl; split16(-0.5f * dsq, vh, vl);
    unsigned* rec = stw + c * 10;
    *(uint2*)(rec + 0) = make_uint2(U[0], U[1]);
    *(uint2*)(rec + 2) = make_uint2(U[2], U[3]);
    *(uint2*)(rec + 4) = make_uint2(U[4], U[5]);
    *(uint2*)(rec + 6) = make_uint2(pack2(vh, vl), 0u);
  }
  __syncthreads();
  const int abase = c15 * 10 + quad * 2;
  int cbl = 256, par = 0;
  for (int k = 0; k < ITERS && cbl > 0; ++k) {
    // ---- B-query fragments: 4 tiles/wave, qt = wv + j*4 --------------------
    half8 bq[4];
    int lq[4];
#pragma unroll
    for (int j = 0; j < 4; ++j) {
      int qt = wv + j * 4;
      int pos = qt * 16 + c15;
      bool act = pos < cbl;
      int l = act ? (int)slist[par][pos] : 0;
      lq[j] = l;
      uint4 wds = make_uint4(0u, 0u, 0u, 0u);
      if (act) {
        if (quad < 3) {
          unsigned short h, lo2;
          float f0 = fdat[l][quad*2], f1 = fdat[l][quad*2+1];
          split16(f0, h, lo2); wds.x = pack2(h, h); wds.y = pack2(lo2, lo2);
          split16(f1, h, lo2); wds.z = pack2(h, h); wds.w = pack2(lo2, lo2);
        } else {
          wds.x = 0x3C003C00u;  // ones in the dsq slot (k=24,25)
        }
      }
      bq[j] = __builtin_bit_cast(half8, wds);
    }
    // ---- diag via gathered-A rows (bit-identical column dot products) ------
#pragma unroll
    for (int j = 0; j < 4; ++j) {
      int row = n0 + lq[j];
      uint2 u = *(const uint2*)(stw + row * 10 + quad * 2);
      unsigned e1 = q3 ? u.y : u.x;
      half8 ag = __builtin_bit_cast(half8, make_uint4(u.x, e1, u.y, u.y));
      f32x4 z = {0.f, 0.f, 0.f, 0.f};
      f32x4 dacc = __builtin_amdgcn_mfma_f32_16x16x32_f16(ag, bq[j], z, 0, 0, 0);
      if ((c15 >> 2) == quad) sdiag[wv][j * 16 + c15] = dacc[c15 & 3];
    }
    // ---- sweep all 64 candidate tiles from the resident panel --------------
    float bvq[4];
#pragma unroll
    for (int j = 0; j < 4; ++j) bvq[j] = -__builtin_inff();
    bool full = ((wv + 12) * 16) < cbl;
    if (full) {
#pragma unroll 4
      for (int ct = 0; ct < 64; ++ct) {
        uint2 u = *(const uint2*)(stw + ct * 160 + abase);
        unsigned e1 = q3 ? u.y : u.x;
        half8 ac = __builtin_bit_cast(half8, make_uint4(u.x, e1, u.y, u.y));
        f32x4 z = {0.f, 0.f, 0.f, 0.f};
#pragma unroll
        for (int j = 0; j < 4; ++j) {
          f32x4 acc = __builtin_amdgcn_mfma_f32_16x16x32_f16(ac, bq[j], z, 0, 0, 0);
          float m = fmaxf(fmaxf(acc[0], acc[1]), acc[2]);      // v_max3
          bvq[j] = fmaxf(fmaxf(bvq[j], m), acc[3]);            // v_max3
        }
      }
    } else {
      bool a0t = (wv * 16) < cbl;
      bool a1t = ((wv + 4) * 16) < cbl;
      bool a2t = ((wv + 8) * 16) < cbl;
#pragma unroll 2
      for (int ct = 0; ct < 64; ++ct) {
        uint2 u = *(const uint2*)(stw + ct * 160 + abase);
        unsigned e1 = q3 ? u.y : u.x;
        half8 ac = __builtin_bit_cast(half8, make_uint4(u.x, e1, u.y, u.y));
        f32x4 z = {0.f, 0.f, 0.f, 0.f};
        if (a0t) {
          f32x4 acc = __builtin_amdgcn_mfma_f32_16x16x32_f16(ac, bq[0], z, 0, 0, 0);
          float m = fmaxf(fmaxf(acc[0], acc[1]), acc[2]);
          bvq[0] = fmaxf(fmaxf(bvq[0], m), acc[3]);
        }
        if (a1t) {
          f32x4 acc = __builtin_amdgcn_mfma_f32_16x16x32_f16(ac, bq[1], z, 0, 0, 0);
          float m = fmaxf(fmaxf(acc[0], acc[1]), acc[2]);
          bvq[1] = fmaxf(fmaxf(bvq[1], m), acc[3]);
        }
        if (a2t) {
          f32x4 acc = __builtin_amdgcn_mfma_f32_16x16x32_f16(ac, bq[2], z, 0, 0, 0);
          float m = fmaxf(fmaxf(acc[0], acc[1]), acc[2]);
          bvq[2] = fmaxf(fmaxf(bvq[2], m), acc[3]);
        }
      }
    }
    // ---- combine across quads (per-query full max) -------------------------
#pragma unroll
    for (int j = 0; j < 4; ++j) {
      bvq[j] = fmaxf(bvq[j], __shfl_xor(bvq[j], 16));
      bvq[j] = fmaxf(bvq[j], __shfl_xor(bvq[j], 32));
    }
    // ---- writers: mismatch = rowmax > diag (quad0 lanes); compact ----------
    unsigned long long wmk[4];
    unsigned cw4[4];
    bool mmv[4];
    unsigned tot = 0u;
#pragma unroll
    for (int j = 0; j < 4; ++j) {
      int qt = wv + j * 4;
      int pos = qt * 16 + c15;
      bool mm = false;
      if (quad == 0 && pos < cbl) mm = bvq[j] > sdiag[wv][j * 16 + c15];
      wmk[j] = __ballot(mm ? 1 : 0);
      cw4[j] = (unsigned)__popcll(wmk[j]);
      mmv[j] = mm;
      tot += cw4[j];
    }
    if (tot != 0u) {  // wave-uniform
      unsigned basev = 0u;
      if (lane == 0) basev = atomicAdd(&nmis[k], tot);
      basev = (unsigned)__shfl((int)basev, 0);
      unsigned pref = 0u;
#pragma unroll
      for (int j = 0; j < 4; ++j) {
        if (mmv[j]) {
          int pos = (int)(basev + pref) + __popcll(wmk[j] & ((1ull << lane) - 1ull));
          slist[par ^ 1][pos] = (unsigned short)lq[j];
        }
        pref += cw4[j];
      }
    }
    __syncthreads();
    int newcb = (int)nmis[k];
    // ---- distributed renoise of survivors ----------------------------------
    if (tid < newcb) {
      unsigned kk0 = keys[2*k], kk1 = keys[2*k+1];
      int l = (int)slist[par ^ 1][tid];
      int p = (b << 10) + n0 + l;
      unsigned base6 = (unsigned)p * 6u;
      float z3 = nrm_from_idx(kk0, kk1, base6 + 3u);
      float z4 = nrm_from_idx(kk0, kk1, base6 + 4u);
      float z5 = nrm_from_idx(kk0, kk1, base6 + 5u);
      const float* dpp = data + (size_t)p * 6;
      fdat[l][3] = __fadd_rn(__fmul_rn(aa, dpp[3]), __fmul_rn(ssv, z3));
      fdat[l][4] = __fadd_rn(__fmul_rn(aa, dpp[4]), __fmul_rn(ssv, z4));
      fdat[l][5] = __fadd_rn(__fmul_rn(aa, dpp[5]), __fmul_rn(ssv, z5));
      lmask[l] |= (unsigned char)(1u << k);
    }
    __syncthreads();
    par ^= 1; cbl = newcb;
  }
  maskg[(b << 10) + n0 + tid] = lmask[tid];
  if (tid < ITERS) cntg[tid * 512 + (int)blockIdx.x] = nmis[tid];
}

// ---- kernel 4: finalize — exact cont gate + noise materialization ----------
__global__ __launch_bounds__(256) void k_final(
    const float* __restrict__ data, const float* __restrict__ noise0,
    const int* __restrict__ ts, const float* __restrict__ sacp,
    const float* __restrict__ s1m, const unsigned* __restrict__ keys,
    const unsigned* __restrict__ cntg, const unsigned char* __restrict__ maskg,
    float* __restrict__ noise_f, float* __restrict__ noisy_f) {
  __shared__ int ksh;
  int tid = (int)threadIdx.x;
  if (tid < 64) {
    int ks = ITERS;
    for (int k2 = 0; k2 < ITERS; ++k2) {
      unsigned v = 0u;
#pragma unroll
      for (int i = 0; i < 8; ++i) v += cntg[k2 * 512 + i * 64 + tid];
#pragma unroll
      for (int m = 32; m >= 1; m >>= 1) v += (unsigned)__shfl_xor((int)v, m);
      if (v < 10u && ks == ITERS) ks = k2;  // first failing iteration
    }
    if (tid == 0) ksh = ks;
  }
  __syncthreads();
  int kstar = ksh;
  unsigned gate = (kstar >= ITERS) ? 0xFFu : ((1u << kstar) - 1u);
  int p = (int)blockIdx.x * 256 + tid;
  int b = p >> 10;
  int t = ts[b];
  float aa = sacp[t], ssv = s1m[t];
  unsigned m = (unsigned)maskg[p] & gate;
  float z3, z4, z5;
  if (m) {
    int j = 31 - __clz((int)m);  // last applied renoise iteration
    unsigned base6 = (unsigned)p * 6u;
    unsigned kk0 = keys[2*j], kk1 = keys[2*j+1];
    z3 = nrm_from_idx(kk0, kk1, base6 + 3u);
    z4 = nrm_from_idx(kk0, kk1, base6 + 4u);
    z5 = nrm_from_idx(kk0, kk1, base6 + 5u);
  } else {
    const float* np0 = noise0 + (size_t)p * 6;
    z3 = np0[3]; z4 = np0[4]; z5 = np0[5];
  }
  const float* dp = data + (size_t)p * 6;
  noise_f[p*3+0] = z3; noise_f[p*3+1] = z4; noise_f[p*3+2] = z5;
  noisy_f[p*3+0] = __fadd_rn(__fmul_rn(aa, dp[3]), __fmul_rn(ssv, z3));
  noisy_f[p*3+1] = __fadd_rn(__fmul_rn(aa, dp[4]), __fmul_rn(ssv, z4));
  noisy_f[p*3+2] = __fadd_rn(__fmul_rn(aa, dp[5]), __fmul_rn(ssv, z5));
}

// ---- kernel 5: MLP + masked SE — j-loop split across the 4 waves -----------
__global__ __launch_bounds__(256) void k_loss(
    const float* __restrict__ data, const float* __restrict__ noise_f,
    const float* __restrict__ noisy_f, const float* __restrict__ biasb,
    const float4* __restrict__ PA, const float4* __restrict__ PB,
    const float* __restrict__ PC, const float* __restrict__ b2,
    float* __restrict__ part) {
  __shared__ float4 sA[HID];
  __shared__ float4 sB[HID];
  __shared__ float2 sCb[HID];
  __shared__ float pp[4][3][256];  // per-wave partials
  __shared__ float red[4];
  int b = blockIdx.x >> 2, qq = blockIdx.x & 3;
  int tid = (int)threadIdx.x;
  int wv = tid >> 6, lane = tid & 63;
  for (int j = tid; j < HID; j += 256) {
    sA[j] = PA[j]; sB[j] = PB[j];
    sCb[j] = make_float2(PC[j], biasb[(size_t)b * HID + j]);
  }
  __syncthreads();
  int p0 = (b << 10) + qq * 256;
  float x[4][6];
  float a0[4], a1[4], a2[4];
#pragma unroll
  for (int q = 0; q < 4; ++q) {
    int p = p0 + q * 64 + lane;
    x[q][0] = data[p*6+0]; x[q][1] = data[p*6+1]; x[q][2] = data[p*6+2];
    x[q][3] = noisy_f[p*3+0]; x[q][4] = noisy_f[p*3+1]; x[q][5] = noisy_f[p*3+2];
    a0[q] = 0.f; a1[q] = 0.f; a2[q] = 0.f;
  }
  int j0 = wv * 128;
#pragma unroll 2
  for (int jj = 0; jj < 128; ++jj) {
    int j = j0 + jj;
    float4 A = sA[j];
    float4 Bv = sB[j];
    float2 Cb = sCb[j];
#pragma unroll
    for (int q = 0; q < 4; ++q) {
      float s = x[q][0] * A.x;
      s = fmaf(x[q][1], A.y, s); s = fmaf(x[q][2], A.z, s);
      s = fmaf(x[q][3], A.w, s); s = fmaf(x[q][4], Bv.x, s);
      s = fmaf(x[q][5], Bv.y, s);
      s += Cb.y;
      float h = ftanh(s);
      a0[q] = fmaf(h, Bv.z, a0[q]);
      a1[q] = fmaf(h, Bv.w, a1[q]);
      a2[q] = fmaf(h, Cb.x, a2[q]);
    }
  }
#pragma unroll
  for (int q = 0; q < 4; ++q) {
    pp[wv][0][q * 64 + lane] = a0[q];
    pp[wv][1][q * 64 + lane] = a1[q];
    pp[wv][2][q * 64 + lane] = a2[q];
  }
  __syncthreads();
  int p = p0 + tid;
  float f0 = (pp[0][0][tid] + pp[1][0][tid] + pp[2][0][tid] + pp[3][0][tid])
             + b2[3] - noise_f[p*3+0];
  float f1 = (pp[0][1][tid] + pp[1][1][tid] + pp[2][1][tid] + pp[3][1][tid])
             + b2[4] - noise_f[p*3+1];
  float f2 = (pp[0][2][tid] + pp[1][2][tid] + pp[2][2][tid] + pp[3][2][tid])
             + b2[5] - noise_f[p*3+2];
  float lsum = f0 * f0;
  lsum = fmaf(f1, f1, lsum);
  lsum = fmaf(f2, f2, lsum);
#pragma unroll
  for (int off = 32; off > 0; off >>= 1) lsum += __shfl_down(lsum, off);
  if ((tid & 63) == 0) red[tid >> 6] = lsum;
  __syncthreads();
  if (tid == 0) part[blockIdx.x] = red[0] + red[1] + red[2] + red[3];
}

// ---- kernel 6: final reduce ------------------------------------------------
__global__ void k_red(const float* __restrict__ part, float* __restrict__ out) {
  int b = (int)threadIdx.x;
  if (b < BS) {
    out[b] = (part[4*b] + part[4*b+1] + part[4*b+2] + part[4*b+3]) / 3072.0f;
  }
}

// ---------------------------------------------------------------------------
extern "C" void kernel_launch(void* const* d_in, const int* in_sizes, int n_in,
                              void* d_out, int out_size, void* d_ws, size_t ws_size,
                              hipStream_t stream) {
  (void)in_sizes; (void)n_in; (void)out_size; (void)ws_size;
  const float* data    = (const float*)d_in[0];
  const float* context = (const float*)d_in[1];
  const float* noise0  = (const float*)d_in[2];
  const float* W1      = (const float*)d_in[3];
  const float* Wc      = (const float*)d_in[4];
  const float* Wt      = (const float*)d_in[5];
  const float* b1      = (const float*)d_in[6];
  const float* W2      = (const float*)d_in[7];
  const float* b2      = (const float*)d_in[8];
  const int*   ts      = (const int*)d_in[9];
  float* out = (float*)d_out;

  char* w = (char*)d_ws;
  float*    sacp   = (float*)(w + OFF_SACP);
  float*    s1m    = (float*)(w + OFF_S1M);
  unsigned* keys   = (unsigned*)(w + OFF_KEYS);
  unsigned* cntg   = (unsigned*)(w + OFF_CNTG);
  unsigned char* maskg = (unsigned char*)(w + OFF_MASK);
  float*    noisef = (float*)(w + OFF_NOISE);
  float*    noisyf = (float*)(w + OFF_NOISY);
  float*    biasb  = (float*)(w + OFF_BIAS);
  float4*   PA     = (float4*)(w + OFF_PA);
  float4*   PB     = (float4*)(w + OFF_PB);
  float*    PC     = (float*)(w + OFF_PC);
  float*    part   = (float*)(w + OFF_PART);

  k_init<<<1, 256, 0, stream>>>(sacp, s1m, keys);
  k_biaspack<<<257, 256, 0, stream>>>(context, Wc, Wt, b1, ts, biasb,
                                      W1, W2, PA, PB, PC);
  k_renoise<<<512, 256, 0, stream>>>(data, noise0, ts, sacp, s1m, keys,
                                     cntg, maskg);
  k_final<<<512, 256, 0, stream>>>(data, noise0, ts, sacp, s1m, keys,
                                   cntg, maskg, noisef, noisyf);
  k_loss<<<512, 256, 0, stream>>>(data, noisef, noisyf, biasb, PA, PB, PC, b2, part);
  k_red<<<1, 128, 0, stream>>>(part, out);
}

// Round 9
// 214.163 us; speedup vs baseline: 1.9637x; 1.0000x over previous
//
#include <hip/hip_runtime.h>
#include <hip/hip_bf16.h>
#include <hip/hip_fp16.h>
#include <math.h>

// ---------------------------------------------------------------------------
// Diffusion renoise-loop + conditional MLP loss, MI355X (gfx950).
// RNG: threefry_partitionable (bit-exact, absmax 0.0 rounds 1-8).
// Round 9: candidate K-words hoisted into REGISTERS (64 x uint2/lane, built
// once, reused all 8 iterations) -- round-8's per-ct ds_read_b64 latency was
// the ~100us wall (2 waves/SIMD couldn't hide 64 serial LDS loads/iter).
// Also: e1 cndmask removed (B K-words 13-15 are zero -> (ux,ux,uy,uy) is
// bit-identical). LDS panel kept only for the 4 diag gathers/iter.
#define BS   128
#define NS   1024
#define HID  512
#define CTX  128
#define TT   100
#define ITERS 8

// ---- workspace layout (bytes) ---------------------------------------------
constexpr size_t OFF_SACP  = 0;         // 100 f32
constexpr size_t OFF_S1M   = 512;       // 100 f32
constexpr size_t OFF_KEYS  = 1024;      // 16 u32
constexpr size_t OFF_CNTG  = 1152;      // u32[8][512] -> 17536
constexpr size_t OFF_MASK  = 17536;     // u8[131072] -> 148608
constexpr size_t OFF_NOISE = 262144;    // f32[128*1024*3] -> 1835008
constexpr size_t OFF_NOISY = 1835008;   // f32[128*1024*3] -> 3407872
constexpr size_t OFF_BIAS  = 3407872;   // f32[128*512] -> 3670016
constexpr size_t OFF_PA    = 3670016;   // float4[512] -> 3678208
constexpr size_t OFF_PB    = 3678208;   // float4[512] -> 3686400
constexpr size_t OFF_PC    = 3686400;   // f32[512]   -> 3688448
constexpr size_t OFF_PART  = 3688448;   // f32[512]   -> 3690496 (~3.7 MB)

typedef __attribute__((ext_vector_type(8))) _Float16 half8;
typedef __attribute__((ext_vector_type(4))) float f32x4;

// ---- threefry2x32-20 -------------------------------------------------------
__device__ __forceinline__ unsigned rotl32(unsigned x, int r) {
  return (x << r) | (x >> (32 - r));
}
__device__ __forceinline__ void tf2x32(unsigned k0, unsigned k1,
                                       unsigned x0, unsigned x1,
                                       unsigned& o0, unsigned& o1) {
  unsigned k2 = k0 ^ k1 ^ 0x1BD11BDAu;
  x0 += k0; x1 += k1;
#define TF_R4(a,b,c,d) \
  x0 += x1; x1 = rotl32(x1,(a)); x1 ^= x0; \
  x0 += x1; x1 = rotl32(x1,(b)); x1 ^= x0; \
  x0 += x1; x1 = rotl32(x1,(c)); x1 ^= x0; \
  x0 += x1; x1 = rotl32(x1,(d)); x1 ^= x0;
  TF_R4(13,15,26,6)   x0 += k1; x1 += k2 + 1u;
  TF_R4(17,29,16,24)  x0 += k2; x1 += k0 + 2u;
  TF_R4(13,15,26,6)   x0 += k0; x1 += k1 + 3u;
  TF_R4(17,29,16,24)  x0 += k1; x1 += k2 + 4u;
  TF_R4(13,15,26,6)   x0 += k2; x1 += k0 + 5u;
#undef TF_R4
  o0 = x0; o1 = x1;
}

__device__ __forceinline__ float bits_to_u(unsigned bits) {
  float f = __uint_as_float((bits >> 9) | 0x3f800000u) - 1.0f;
  float u = f * 2.0f + (-0.99999994f);
  return fmaxf(-0.99999994f, u);
}

__device__ __forceinline__ float nrm_from_idx(unsigned k0, unsigned k1, unsigned idx) {
  unsigned o0, o1;
  tf2x32(k0, k1, 0u, idx, o0, o1);
  return 1.41421356f * erfinvf(bits_to_u(o0 ^ o1));
}

__device__ __forceinline__ float ftanh(float x) {
  float e = __expf(2.0f * x);
  float r = __builtin_amdgcn_rcpf(e + 1.0f);
  return fmaf(-2.0f, r, 1.0f);
}

// fp16 hi/lo split: x ~= hi + lo with |err| <~ 2^-23 |x|
__device__ __forceinline__ void split16(float x, unsigned short& hi, unsigned short& lo) {
  __half h = __float2half(x);
  float hf = __half2float(h);
  __half l = __float2half(x - hf);
  hi = __half_as_ushort(h);
  lo = __half_as_ushort(l);
}
__device__ __forceinline__ unsigned pack2(unsigned short a, unsigned short b) {
  return (unsigned)a | ((unsigned)b << 16);
}

// ---- kernel 1: tables + iteration keys -------------------------------------
__global__ void k_init(float* __restrict__ sacp, float* __restrict__ s1m,
                       unsigned* __restrict__ keys) {
  __shared__ double omb[TT];
  int t = threadIdx.x;
  if (t < TT) {
    const double PI = 3.14159265358979323846;
    double t0 = (double)t / TT, t1 = (double)(t + 1) / TT;
    double c0 = cos((t0 + 0.008) / 1.008 * PI * 0.5); double ab0 = c0 * c0;
    double c1 = cos((t1 + 0.008) / 1.008 * PI * 0.5); double ab1 = c1 * c1;
    double beta = 1.0 - ab1 / ab0;
    if (beta > 0.999) beta = 0.999;
    omb[t] = 1.0 - beta;
  }
  __syncthreads();
  if (t < TT) {
    double acp = 1.0;
    for (int i = 0; i <= t; ++i) acp *= omb[i];
    sacp[t] = (float)sqrt(acp);
    s1m[t]  = (float)sqrt(1.0 - acp);
  }
  if (t >= 128 && t < 128 + ITERS) {
    int k = t - 128;
    unsigned o0, o1;
    tf2x32(0u, 42u, 0u, (unsigned)k, o0, o1);
    keys[2*k] = o0; keys[2*k+1] = o1;
  }
}

// ---- kernel 2: bias = c@Wc + (t/T)*Wt + b1 (ctx via LDS) + weight pack -----
__global__ __launch_bounds__(256) void k_biaspack(
    const float* __restrict__ ctx, const float* __restrict__ Wc,
    const float* __restrict__ Wt, const float* __restrict__ b1,
    const int* __restrict__ ts, float* __restrict__ biasb,
    const float* __restrict__ W1, const float* __restrict__ W2,
    float4* __restrict__ PA, float4* __restrict__ PB, float* __restrict__ PC) {
  if (blockIdx.x == 256) {
    for (int j = threadIdx.x; j < HID; j += 256) {
      PA[j] = make_float4(W1[j], W1[512 + j], W1[1024 + j], W1[1536 + j]);
      PB[j] = make_float4(W1[2048 + j], W1[2560 + j], W2[j*6 + 3], W2[j*6 + 4]);
      PC[j] = W2[j*6 + 5];
    }
    return;
  }
  __shared__ float sc[CTX];
  int b = blockIdx.x >> 1;
  int j = (blockIdx.x & 1) * 256 + (int)threadIdx.x;
  if (threadIdx.x < CTX) sc[threadIdx.x] = ctx[(size_t)b * CTX + threadIdx.x];
  __syncthreads();
  float acc = 0.f;
  for (int q = 0; q < CTX; ++q) acc = fmaf(sc[q], Wc[q * HID + j], acc);
  float temb = (float)ts[b] / 100.0f;
  biasb[b * HID + j] = acc + temb * Wt[j] + b1[j];
}

// ---- kernel 3: renoise loop — 512 blocks (4 q-slices x 128 batches) --------
// A = candidates (64 x uint2 PER-LANE REGISTERS, iteration-invariant),
// B = queries (rebuilt per iter). Rowmax collapses via v_max3; diag via
// gathered-A MFMA from the LDS panel (bit-identical). Speculative cont.
__global__ __launch_bounds__(256, 2) void k_renoise(
    const float* __restrict__ data, const float* __restrict__ noise0,
    const int* __restrict__ ts, const float* __restrict__ sacp,
    const float* __restrict__ s1m, const unsigned* __restrict__ keys,
    unsigned* __restrict__ cntg, unsigned char* __restrict__ maskg) {
  __shared__ unsigned stw[10240];            // 40 KB: 1024 records x 10 words
  __shared__ float fdat[256][6];             // 6 KB
  __shared__ unsigned short slist[2][256];   // 1 KB
  __shared__ float sdiag[4][64];             // 1 KB
  __shared__ unsigned char lmask[256];
  __shared__ unsigned nmis[ITERS];
  const int b = blockIdx.x & 127, qb = blockIdx.x >> 7;
  const int tid = (int)threadIdx.x;
  const int wv = tid >> 6, lane = tid & 63;
  const int c15 = lane & 15, quad = lane >> 4;
  const int n0 = qb * 256;
  const int t = ts[b];
  const float aa = sacp[t], ssv = s1m[t];
  // ---- init query state ----------------------------------------------------
  {
    int p = (b << 10) + n0 + tid;
    const float* dp = data + (size_t)p * 6;
    const float* np0 = noise0 + (size_t)p * 6;
    fdat[tid][0] = dp[0]; fdat[tid][1] = dp[1]; fdat[tid][2] = dp[2];
    fdat[tid][3] = __fadd_rn(__fmul_rn(aa, dp[3]), __fmul_rn(ssv, np0[3]));
    fdat[tid][4] = __fadd_rn(__fmul_rn(aa, dp[4]), __fmul_rn(ssv, np0[4]));
    fdat[tid][5] = __fadd_rn(__fmul_rn(aa, dp[5]), __fmul_rn(ssv, np0[5]));
    slist[0][tid] = (unsigned short)tid;
    lmask[tid] = 0;
    if (tid < ITERS) nmis[tid] = 0u;
  }
  // ---- build dedup candidate panel: record = [U0..U5, V, 0, pad, pad] ------
  for (int ii = 0; ii < 4; ++ii) {
    int c = ii * 256 + tid;
    const float2* dp2 = (const float2*)(data + ((size_t)(b << 10) + c) * 6);
    float2 v0 = dp2[0], v1 = dp2[1], v2 = dp2[2];
    float dd[6] = {v0.x, v0.y, v1.x, v1.y, v2.x, v2.y};
    float dsq = dd[0]*dd[0];
    dsq = fmaf(dd[1], dd[1], dsq); dsq = fmaf(dd[2], dd[2], dsq);
    dsq = fmaf(dd[3], dd[3], dsq); dsq = fmaf(dd[4], dd[4], dsq);
    dsq = fmaf(dd[5], dd[5], dsq);
    unsigned U[6];
#pragma unroll
    for (int d = 0; d < 6; ++d) {
      unsigned short hi, lo; split16(dd[d], hi, lo);
      U[d] = pack2(hi, lo);
    }
    unsigned short vh, vl; split16(-0.5f * dsq, vh, vl);
    unsigned* rec = stw + c * 10;
    *(uint2*)(rec + 0) = make_uint2(U[0], U[1]);
    *(uint2*)(rec + 2) = make_uint2(U[2], U[3]);
    *(uint2*)(rec + 4) = make_uint2(U[4], U[5]);
    *(uint2*)(rec + 6) = make_uint2(pack2(vh, vl), 0u);
  }
  __syncthreads();
  // ---- hoist this lane's 64 candidate K-word pairs into registers ----------
  const int abase = c15 * 10 + quad * 2;
  unsigned cux[64], cuy[64];
#pragma unroll
  for (int ct = 0; ct < 64; ++ct) {
    uint2 u = *(const uint2*)(stw + ct * 160 + abase);
    cux[ct] = u.x; cuy[ct] = u.y;
  }
  int cbl = 256, par = 0;
  for (int k = 0; k < ITERS && cbl > 0; ++k) {
    // ---- B-query fragments: 4 tiles/wave, qt = wv + j*4 --------------------
    half8 bq[4];
    int lq[4];
#pragma unroll
    for (int j = 0; j < 4; ++j) {
      int qt = wv + j * 4;
      int pos = qt * 16 + c15;
      bool act = pos < cbl;
      int l = act ? (int)slist[par][pos] : 0;
      lq[j] = l;
      uint4 wds = make_uint4(0u, 0u, 0u, 0u);
      if (act) {
        if (quad < 3) {
          unsigned short h, lo2;
          float f0 = fdat[l][quad*2], f1 = fdat[l][quad*2+1];
          split16(f0, h, lo2); wds.x = pack2(h, h); wds.y = pack2(lo2, lo2);
          split16(f1, h, lo2); wds.z = pack2(h, h); wds.w = pack2(lo2, lo2);
        } else {
          wds.x = 0x3C003C00u;  // ones in the dsq slot; words 13..15 stay 0
        }
      }
      bq[j] = __builtin_bit_cast(half8, wds);
    }
    // ---- diag via gathered-A rows (bit-identical column dot products) ------
#pragma unroll
    for (int j = 0; j < 4; ++j) {
      int row = n0 + lq[j];
      uint2 u = *(const uint2*)(stw + row * 10 + quad * 2);
      // (ux,ux,uy,uy): words 13-15 of B are zero, so q3's word13 is inert
      half8 ag = __builtin_bit_cast(half8, make_uint4(u.x, u.x, u.y, u.y));
      f32x4 z = {0.f, 0.f, 0.f, 0.f};
      f32x4 dacc = __builtin_amdgcn_mfma_f32_16x16x32_f16(ag, bq[j], z, 0, 0, 0);
      if ((c15 >> 2) == quad) sdiag[wv][j * 16 + c15] = dacc[c15 & 3];
    }
    // ---- sweep: all 64 candidate tiles from REGISTERS ----------------------
    float bvq[4];
#pragma unroll
    for (int j = 0; j < 4; ++j) bvq[j] = -__builtin_inff();
    if ((wv * 16) < cbl) {  // wave-uniform: wave has >=1 active query tile
#pragma unroll
      for (int ct = 0; ct < 64; ++ct) {
        half8 ac = __builtin_bit_cast(half8,
                     make_uint4(cux[ct], cux[ct], cuy[ct], cuy[ct]));
        f32x4 z = {0.f, 0.f, 0.f, 0.f};
#pragma unroll
        for (int j = 0; j < 4; ++j) {
          f32x4 acc = __builtin_amdgcn_mfma_f32_16x16x32_f16(ac, bq[j], z, 0, 0, 0);
          float m = fmaxf(fmaxf(acc[0], acc[1]), acc[2]);      // v_max3
          bvq[j] = fmaxf(fmaxf(bvq[j], m), acc[3]);            // v_max3
        }
      }
    }
    // ---- combine across quads (per-query full max) -------------------------
#pragma unroll
    for (int j = 0; j < 4; ++j) {
      bvq[j] = fmaxf(bvq[j], __shfl_xor(bvq[j], 16));
      bvq[j] = fmaxf(bvq[j], __shfl_xor(bvq[j], 32));
    }
    // ---- writers: mismatch = rowmax > diag (quad0 lanes); compact ----------
    unsigned long long wmk[4];
    unsigned cw4[4];
    bool mmv[4];
    unsigned tot = 0u;
#pragma unroll
    for (int j = 0; j < 4; ++j) {
      int qt = wv + j * 4;
      int pos = qt * 16 + c15;
      bool mm = false;
      if (quad == 0 && pos < cbl) mm = bvq[j] > sdiag[wv][j * 16 + c15];
      wmk[j] = __ballot(mm ? 1 : 0);
      cw4[j] = (unsigned)__popcll(wmk[j]);
      mmv[j] = mm;
      tot += cw4[j];
    }
    if (tot != 0u) {  // wave-uniform
      unsigned basev = 0u;
      if (lane == 0) basev = atomicAdd(&nmis[k], tot);
      basev = (unsigned)__shfl((int)basev, 0);
      unsigned pref = 0u;
#pragma unroll
      for (int j = 0; j < 4; ++j) {
        if (mmv[j]) {
          int pos = (int)(basev + pref) + __popcll(wmk[j] & ((1ull << lane) - 1ull));
          slist[par ^ 1][pos] = (unsigned short)lq[j];
        }
        pref += cw4[j];
      }
    }
    __syncthreads();
    int newcb = (int)nmis[k];
    // ---- distributed renoise of survivors ----------------------------------
    if (tid < newcb) {
      unsigned kk0 = keys[2*k], kk1 = keys[2*k+1];
      int l = (int)slist[par ^ 1][tid];
      int p = (b << 10) + n0 + l;
      unsigned base6 = (unsigned)p * 6u;
      float z3 = nrm_from_idx(kk0, kk1, base6 + 3u);
      float z4 = nrm_from_idx(kk0, kk1, base6 + 4u);
      float z5 = nrm_from_idx(kk0, kk1, base6 + 5u);
      const float* dpp = data + (size_t)p * 6;
      fdat[l][3] = __fadd_rn(__fmul_rn(aa, dpp[3]), __fmul_rn(ssv, z3));
      fdat[l][4] = __fadd_rn(__fmul_rn(aa, dpp[4]), __fmul_rn(ssv, z4));
      fdat[l][5] = __fadd_rn(__fmul_rn(aa, dpp[5]), __fmul_rn(ssv, z5));
      lmask[l] |= (unsigned char)(1u << k);
    }
    __syncthreads();
    par ^= 1; cbl = newcb;
  }
  maskg[(b << 10) + n0 + tid] = lmask[tid];
  if (tid < ITERS) cntg[tid * 512 + (int)blockIdx.x] = nmis[tid];
}

// ---- kernel 4: finalize — exact cont gate + noise materialization ----------
__global__ __launch_bounds__(256) void k_final(
    const float* __restrict__ data, const float* __restrict__ noise0,
    const int* __restrict__ ts, const float* __restrict__ sacp,
    const float* __restrict__ s1m, const unsigned* __restrict__ keys,
    const unsigned* __restrict__ cntg, const unsigned char* __restrict__ maskg,
    float* __restrict__ noise_f, float* __restrict__ noisy_f) {
  __shared__ int ksh;
  int tid = (int)threadIdx.x;
  if (tid < 64) {
    int ks = ITERS;
    for (int k2 = 0; k2 < ITERS; ++k2) {
      unsigned v = 0u;
#pragma unroll
      for (int i = 0; i < 8; ++i) v += cntg[k2 * 512 + i * 64 + tid];
#pragma unroll
      for (int m = 32; m >= 1; m >>= 1) v += (unsigned)__shfl_xor((int)v, m);
      if (v < 10u && ks == ITERS) ks = k2;  // first failing iteration
    }
    if (tid == 0) ksh = ks;
  }
  __syncthreads();
  int kstar = ksh;
  unsigned gate = (kstar >= ITERS) ? 0xFFu : ((1u << kstar) - 1u);
  int p = (int)blockIdx.x * 256 + tid;
  int b = p >> 10;
  int t = ts[b];
  float aa = sacp[t], ssv = s1m[t];
  unsigned m = (unsigned)maskg[p] & gate;
  float z3, z4, z5;
  if (m) {
    int j = 31 - __clz((int)m);  // last applied renoise iteration
    unsigned base6 = (unsigned)p * 6u;
    unsigned kk0 = keys[2*j], kk1 = keys[2*j+1];
    z3 = nrm_from_idx(kk0, kk1, base6 + 3u);
    z4 = nrm_from_idx(kk0, kk1, base6 + 4u);
    z5 = nrm_from_idx(kk0, kk1, base6 + 5u);
  } else {
    const float* np0 = noise0 + (size_t)p * 6;
    z3 = np0[3]; z4 = np0[4]; z5 = np0[5];
  }
  const float* dp = data + (size_t)p * 6;
  noise_f[p*3+0] = z3; noise_f[p*3+1] = z4; noise_f[p*3+2] = z5;
  noisy_f[p*3+0] = __fadd_rn(__fmul_rn(aa, dp[3]), __fmul_rn(ssv, z3));
  noisy_f[p*3+1] = __fadd_rn(__fmul_rn(aa, dp[4]), __fmul_rn(ssv, z4));
  noisy_f[p*3+2] = __fadd_rn(__fmul_rn(aa, dp[5]), __fmul_rn(ssv, z5));
}

// ---- kernel 5: MLP + masked SE — j-loop split across the 4 waves -----------
__global__ __launch_bounds__(256) void k_loss(
    const float* __restrict__ data, const float* __restrict__ noise_f,
    const float* __restrict__ noisy_f, const float* __restrict__ biasb,
    const float4* __restrict__ PA, const float4* __restrict__ PB,
    const float* __restrict__ PC, const float* __restrict__ b2,
    float* __restrict__ part) {
  __shared__ float4 sA[HID];
  __shared__ float4 sB[HID];
  __shared__ float2 sCb[HID];
  __shared__ float pp[4][3][256];  // per-wave partials
  __shared__ float red[4];
  int b = blockIdx.x >> 2, qq = blockIdx.x & 3;
  int tid = (int)threadIdx.x;
  int wv = tid >> 6, lane = tid & 63;
  for (int j = tid; j < HID; j += 256) {
    sA[j] = PA[j]; sB[j] = PB[j];
    sCb[j] = make_float2(PC[j], biasb[(size_t)b * HID + j]);
  }
  __syncthreads();
  int p0 = (b << 10) + qq * 256;
  float x[4][6];
  float a0[4], a1[4], a2[4];
#pragma unroll
  for (int q = 0; q < 4; ++q) {
    int p = p0 + q * 64 + lane;
    x[q][0] = data[p*6+0]; x[q][1] = data[p*6+1]; x[q][2] = data[p*6+2];
    x[q][3] = noisy_f[p*3+0]; x[q][4] = noisy_f[p*3+1]; x[q][5] = noisy_f[p*3+2];
    a0[q] = 0.f; a1[q] = 0.f; a2[q] = 0.f;
  }
  int j0 = wv * 128;
#pragma unroll 2
  for (int jj = 0; jj < 128; ++jj) {
    int j = j0 + jj;
    float4 A = sA[j];
    float4 Bv = sB[j];
    float2 Cb = sCb[j];
#pragma unroll
    for (int q = 0; q < 4; ++q) {
      float s = x[q][0] * A.x;
      s = fmaf(x[q][1], A.y, s); s = fmaf(x[q][2], A.z, s);
      s = fmaf(x[q][3], A.w, s); s = fmaf(x[q][4], Bv.x, s);
      s = fmaf(x[q][5], Bv.y, s);
      s += Cb.y;
      float h = ftanh(s);
      a0[q] = fmaf(h, Bv.z, a0[q]);
      a1[q] = fmaf(h, Bv.w, a1[q]);
      a2[q] = fmaf(h, Cb.x, a2[q]);
    }
  }
#pragma unroll
  for (int q = 0; q < 4; ++q) {
    pp[wv][0][q * 64 + lane] = a0[q];
    pp[wv][1][q * 64 + lane] = a1[q];
    pp[wv][2][q * 64 + lane] = a2[q];
  }
  __syncthreads();
  int p = p0 + tid;
  float f0 = (pp[0][0][tid] + pp[1][0][tid] + pp[2][0][tid] + pp[3][0][tid])
             + b2[3] - noise_f[p*3+0];
  float f1 = (pp[0][1][tid] + pp[1][1][tid] + pp[2][1][tid] + pp[3][1][tid])
             + b2[4] - noise_f[p*3+1];
  float f2 = (pp[0][2][tid] + pp[1][2][tid] + pp[2][2][tid] + pp[3][2][tid])
             + b2[5] - noise_f[p*3+2];
  float lsum = f0 * f0;
  lsum = fmaf(f1, f1, lsum);
  lsum = fmaf(f2, f2, lsum);
#pragma unroll
  for (int off = 32; off > 0; off >>= 1) lsum += __shfl_down(lsum, off);
  if ((tid & 63) == 0) red[tid >> 6] = lsum;
  __syncthreads();
  if (tid == 0) part[blockIdx.x] = red[0] + red[1] + red[2] + red[3];
}

// ---- kernel 6: final reduce ------------------------------------------------
__global__ void k_red(const float* __restrict__ part, float* __restrict__ out) {
  int b = (int)threadIdx.x;
  if (b < BS) {
    out[b] = (part[4*b] + part[4*b+1] + part[4*b+2] + part[4*b+3]) / 3072.0f;
  }
}

// ---------------------------------------------------------------------------
extern "C" void kernel_launch(void* const* d_in, const int* in_sizes, int n_in,
                              void* d_out, int out_size, void* d_ws, size_t ws_size,
                              hipStream_t stream) {
  (void)in_sizes; (void)n_in; (void)out_size; (void)ws_size;
  const float* data    = (const float*)d_in[0];
  const float* context = (const float*)d_in[1];
  const float* noise0  = (const float*)d_in[2];
  const float* W1      = (const float*)d_in[3];
  const float* Wc      = (const float*)d_in[4];
  const float* Wt      = (const float*)d_in[5];
  const float* b1      = (const float*)d_in[6];
  const float* W2      = (const float*)d_in[7];
  const float* b2      = (const float*)d_in[8];
  const int*   ts      = (const int*)d_in[9];
  float* out = (float*)d_out;

  char* w = (char*)d_ws;
  float*    sacp   = (float*)(w + OFF_SACP);
  float*    s1m    = (float*)(w + OFF_S1M);
  unsigned* keys   = (unsigned*)(w + OFF_KEYS);
  unsigned* cntg   = (unsigned*)(w + OFF_CNTG);
  unsigned char* maskg = (unsigned char*)(w + OFF_MASK);
  float*    noisef = (float*)(w + OFF_NOISE);
  float*    noisyf = (float*)(w + OFF_NOISY);
  float*    biasb  = (float*)(w + OFF_BIAS);
  float4*   PA     = (float4*)(w + OFF_PA);
  float4*   PB     = (float4*)(w + OFF_PB);
  float*    PC     = (float*)(w + OFF_PC);
  float*    part   = (float*)(w + OFF_PART);

  k_init<<<1, 256, 0, stream>>>(sacp, s1m, keys);
  k_biaspack<<<257, 256, 0, stream>>>(context, Wc, Wt, b1, ts, biasb,
                                      W1, W2, PA, PB, PC);
  k_renoise<<<512, 256, 0, stream>>>(data, noise0, ts, sacp, s1m, keys,
                                     cntg, maskg);
  k_final<<<512, 256, 0, stream>>>(data, noise0, ts, sacp, s1m, keys,
                                   cntg, maskg, noisef, noisyf);
  k_loss<<<512, 256, 0, stream>>>(data, noisef, noisyf, biasb, PA, PB, PC, b2, part);
  k_red<<<1, 128, 0, stream>>>(part, out);
}